// Round 2
// baseline (413.027 us; speedup 1.0000x reference)
//
#include <hip/hip_runtime.h>
#include <math.h>

#define NSAMP 32768
#define NPAD  65536
#define NCH   128
#define NCHAIN 2048

__device__ __forceinline__ float2 cxmul(float2 a, float2 b){
    return make_float2(a.x*b.x - a.y*b.y, a.x*b.y + a.y*b.x);
}

template<int DIR>
__device__ __forceinline__ void fft4v(float2* v, int i0, int i1, int i2, int i3){
    float2 a=v[i0], b=v[i1], c=v[i2], d=v[i3];
    float2 t0 = make_float2(a.x+c.x, a.y+c.y);
    float2 t1 = make_float2(a.x-c.x, a.y-c.y);
    float2 t2 = make_float2(b.x+d.x, b.y+d.y);
    float2 t3 = make_float2(b.x-d.x, b.y-d.y);
    v[i0] = make_float2(t0.x+t2.x, t0.y+t2.y);
    v[i2] = make_float2(t0.x-t2.x, t0.y-t2.y);
    if (DIR < 0) {  // forward: X1 = t1 - i*t3, X3 = t1 + i*t3
        v[i1] = make_float2(t1.x + t3.y, t1.y - t3.x);
        v[i3] = make_float2(t1.x - t3.y, t1.y + t3.x);
    } else {
        v[i1] = make_float2(t1.x - t3.y, t1.y + t3.x);
        v[i3] = make_float2(t1.x + t3.y, t1.y - t3.x);
    }
}

template<int DIR>
__device__ __forceinline__ void twm(float2& v, float c, float s){
    float sy = (DIR<0) ? -s : s;   // forward: e^{-i th} = (cos, -sin)
    v = cxmul(v, make_float2(c, sy));
}

template<int DIR>
__device__ __forceinline__ void fft16r(float2* v){
    const float C1=0.92387953251128674f, S1=0.38268343236508978f, H=0.70710678118654752f;
    fft4v<DIR>(v,0,4,8,12);
    fft4v<DIR>(v,1,5,9,13);
    fft4v<DIR>(v,2,6,10,14);
    fft4v<DIR>(v,3,7,11,15);
    twm<DIR>(v[5],  C1, S1);
    twm<DIR>(v[6],  H,  H);
    twm<DIR>(v[7],  S1, C1);
    twm<DIR>(v[9],  H,  H);
    twm<DIR>(v[10], 0.0f, 1.0f);
    twm<DIR>(v[11], -H, H);
    twm<DIR>(v[13], S1, C1);
    twm<DIR>(v[14], -H, H);
    twm<DIR>(v[15], -C1, -S1);
    fft4v<DIR>(v,0,1,2,3);
    fft4v<DIR>(v,4,5,6,7);
    fft4v<DIR>(v,8,9,10,11);
    fft4v<DIR>(v,12,13,14,15);
    // X[r] at slot ((r&3)<<2)|(r>>2)
}

template<int DIR>
__device__ __forceinline__ void fft8r(float2* v){
    const float H=0.70710678118654752f;
    #pragma unroll
    for (int n1=0;n1<4;n1++){
        float2 t=v[n1], u=v[n1+4];
        v[n1]   = make_float2(t.x+u.x, t.y+u.y);
        v[n1+4] = make_float2(t.x-u.x, t.y-u.y);
    }
    twm<DIR>(v[5], H, H);
    twm<DIR>(v[6], 0.0f, 1.0f);
    twm<DIR>(v[7], -H, H);
    fft4v<DIR>(v,0,1,2,3);
    fft4v<DIR>(v,4,5,6,7);
    // X[r] at slot ((r&1)<<2)|(r>>1)
}

// Stockham DIT pass, radix R, batch via blockIdx.y, array length N = T*R.
template<int R, int DIR>
__global__ __launch_bounds__(256) void mfk_fft(const float2* __restrict__ src,
                                               float2* __restrict__ dst,
                                               int Ns, int T)
{
    int j = blockIdx.x*256 + threadIdx.x;
    if (j >= T) return;
    size_t aoff = (size_t)blockIdx.y * (size_t)T * (size_t)R;
    const float2* x = src + aoff;
    float2* y = dst + aoff;
    float2 v[R];
    #pragma unroll
    for (int r=0;r<R;r++) v[r] = x[j + r*T];
    int jm = j & (Ns-1);
    if (jm) {
        float base = (DIR<0 ? -6.2831853071795864f : 6.2831853071795864f)
                     * ((float)jm / (float)(Ns*R));
        #pragma unroll
        for (int r=1;r<R;r++){
            float s,c; __sincosf(base*(float)r, &s, &c);
            v[r] = cxmul(v[r], make_float2(c,s));
        }
    }
    if (R==16) fft16r<DIR>(v); else fft8r<DIR>(v);
    int idxD = (j & ~(Ns-1))*R + jm;
    float2* yo = y + idxD;
    #pragma unroll
    for (int r=0;r<R;r++){
        int slot = (R==16) ? (((r&3)<<2)|(r>>2)) : (((r&1)<<2)|(r>>1));
        yo[r*Ns] = v[slot];
    }
}

__global__ __launch_bounds__(256) void mfk_r2c(const float* __restrict__ in, float2* __restrict__ out, int n){
    int i = blockIdx.x*256 + threadIdx.x;
    if (i < n) out[i] = make_float2(in[i], 0.0f);
}
__global__ __launch_bounds__(256) void mfk_copy2(const float2* __restrict__ in, float2* __restrict__ out, int n){
    int i = blockIdx.x*256 + threadIdx.x;
    if (i < n) out[i] = in[i];
}

// Per-channel / per-chain parameter setup (no serial walks).
__global__ __launch_bounds__(256) void mfk_setup(const float* __restrict__ EP, const float* __restrict__ MXR,
        const float* __restrict__ RL, float* __restrict__ chP, float* __restrict__ chF,
        float* __restrict__ cum,
        float* __restrict__ mxA, float* __restrict__ rmA)
{
    int q = blockIdx.x*256 + threadIdx.x;
    if (q >= NCHAIN) return;
    int c = q >> 4, h = q & 15;
    const float* P = EP + c*22;
    const float MINF = (float)(20.0/11025.0);
    const float DRF  = (float)(4000.0/11025.0 - 20.0/11025.0);
    const float LSQ  = (float)0.9189385332046727;
    // chain frequency
    float f0m = __fmul_rn(P[4], P[4]);
    float f0s = __fadd_rn(MINF, __fmul_rn(f0m, DRF));
    float fr  = __fmul_rn(f0s, (float)(h+1));
    if (fr >= 1.0f) fr = 0.0f;
    chF[q] = fr;
    // cumprod of res (sequential f32; smooth, non-chaotic)
    float rs = __fadd_rn(__fmul_rn(P[6+h], 0.2f), 0.8f);
    float cp = rs;
    float* crow = cum + (size_t)q*128;
    for (int j=0;j<128;j++){ crow[j] = cp; cp = __fmul_rn(cp, rs); }
    if (h == 0) {
        // freq window params (analytic max-norm: peak at nearest grid point)
        float fm  = __fmul_rn(P[0],P[0]);
        float fmu = __fadd_rn(MINF, __fmul_rn(fm, DRF));
        float fsg = 1e-8f + P[1]*0.1f;
        float fsi = 1.0f/fsg;
        int i0 = (int)floorf(fmu*16384.0f + 0.5f);
        i0 = min(max(i0,0),16384);
        float rg = (float)i0 * (1.0f/16384.0f);
        float tt = (rg - fmu)*fsi;
        float Lc = logf(fsg) + LSQ;
        float sc = expf(-Lc) / (expf(-0.5f*tt*tt - Lc) + 1e-8f);
        // time window params
        float tmu = P[2];
        float tsg = 1e-8f + P[3]*0.1f;
        float tsi = 1.0f/tsg;
        int i1 = (int)floorf(tmu*32767.0f + 0.5f);
        i1 = min(max(i1,0),32767);
        float rg1 = (float)((double)i1 * (1.0/32767.0));
        float tt1 = (rg1 - tmu)*tsi;
        float Lc1 = logf(tsg) + LSQ;
        float sc1 = expf(-Lc1) / (expf(-0.5f*tt1*tt1 - Lc1) + 1e-8f);
        float amp = P[5]*P[5];
        float* o = chP + c*8;
        o[0]=fmu; o[1]=fsi; o[2]=sc; o[3]=tmu; o[4]=tsi; o[5]=sc1; o[6]=amp; o[7]=0.f;
    }
    if (q < 4) {
        int b = q;
        mxA[b] = 1.0f/(1.0f + expf(-MXR[b]));
        const float* rl = RL + b*8;
        float mx = rl[0];
        for (int r=1;r<8;r++) mx = fmaxf(mx, rl[r]);
        float sum=0.f;
        float e[8];
        for (int r=0;r<8;r++){ e[r]=expf(rl[r]-mx); sum+=e[r]; }
        for (int r=0;r<8;r++) rmA[b*8+r] = e[r]/sum;
    }
}

// Build packed spectra for bl_noise inverse FFT: C = Nspec*w(e0) + i*Nspec*w(e1)
__global__ __launch_bounds__(256) void mfk_specwin(const float2* __restrict__ nspec,
        const float* __restrict__ chP, float2* __restrict__ dstA, int g0)
{
    int k = blockIdx.x*256 + threadIdx.x;   // 0..32767
    int p = blockIdx.y;
    int c0 = g0 + 2*p;
    int kw = (k <= 16384) ? k : (32768 - k);
    float rg = (float)kw * (1.0f/16384.0f);
    const float* A = chP + c0*8;
    const float* B = chP + (c0+1)*8;
    float t0 = (rg - A[0])*A[1];
    float w0 = expf(-0.5f*t0*t0)*A[2];
    float t1 = (rg - B[0])*B[1];
    float w1 = expf(-0.5f*t1*t1)*B[2];
    float2 N = nspec[k];
    dstA[(size_t)p*NSAMP + k] = make_float2(N.x*w0 - N.y*w1, N.y*w0 + N.x*w1);
}

// Unpack bl pair, apply time window + amp -> located_raw
__global__ __launch_bounds__(256) void mfk_unpack(const float2* __restrict__ T,
        const float* __restrict__ chP, float* __restrict__ locraw, int g0)
{
    int n = blockIdx.x*256 + threadIdx.x;
    int p = blockIdx.y;
    float2 tv = T[(size_t)p*NSAMP + n];
    float rg = (float)((double)n * (1.0/32767.0));
    #pragma unroll
    for (int s=0; s<2; s++){
        int lc = 2*p + s;
        const float* C = chP + (g0+lc)*8;
        float tt = (rg - C[3])*C[4];
        float ew = expf(-0.5f*tt*tt)*C[5];
        float bl = ((s==0)? tv.x : tv.y) * (1.0f/32768.0f);
        locraw[(size_t)lc*NSAMP + n] = bl*ew*C[6];
    }
}

// resonances: analytic double-exact phase  sin(2*pi*fr*(t+1)); env via interp of cumprod
__global__ __launch_bounds__(256) void mfk_reson(const float* __restrict__ chF,
        const float* __restrict__ cum, float* __restrict__ reson, int g0)
{
    __shared__ float cp3[16][4];
    __shared__ float fsh[16];
    int j  = blockIdx.x;          // frame block 0..127
    int lc = blockIdx.y;          // local channel
    int cg = g0 + lc;
    int tid = threadIdx.x;
    int base = max(j-1, 0);
    if (tid < 16) {
        int q = cg*16 + tid;
        fsh[tid] = chF[q];
        const float* crow = cum + (size_t)q*128;
        cp3[tid][0] = crow[min(base+0,127)];
        cp3[tid][1] = crow[min(base+1,127)];
        cp3[tid][2] = crow[min(base+2,127)];
    }
    __syncthreads();
    int t = j*256 + tid;
    float co = ((float)t + 0.5f)*0.00390625f - 0.5f;
    co = fminf(fmaxf(co, 0.0f), 127.0f);
    int lo = (int)floorf(co);
    float w = co - (float)lo;
    int s0 = lo - base;
    int s1 = min(lo+1, 127) - base;
    double td = (double)(t+1);
    float acc = 0.0f;
    #pragma unroll
    for (int hh=0; hh<16; hh++){
        float env = cp3[hh][s0]*(1.0f-w) + cp3[hh][s1]*w;
        double p = (double)fsh[hh]*td;        // exact (24b*15b mantissa)
        double m = p - floor(p);              // exact phase in revolutions
        acc += env * sinpif(2.0f*(float)m);
    }
    reson[(size_t)lc*NSAMP + t] = acc;
}

__global__ __launch_bounds__(256) void mfk_packZ(const float* __restrict__ locraw,
        const float* __restrict__ reson, float2* __restrict__ A)
{
    int t = blockIdx.x*256 + threadIdx.x;
    int lc = blockIdx.y;
    float2 z = make_float2(0.f,0.f);
    if (t < NSAMP) z = make_float2(locraw[(size_t)lc*NSAMP+t], reson[(size_t)lc*NSAMP+t]);
    A[(size_t)lc*NPAD + t] = z;
}

// Hermitian unpack of packed pair FFT, spectral product, repack pair, scale 1/NPAD
__global__ __launch_bounds__(256) void mfk_product(const float2* __restrict__ Z, float2* __restrict__ Q)
{
    int k = blockIdx.x*256 + threadIdx.x;
    int p = blockIdx.y;
    const float2* z0 = Z + (size_t)(2*p)*NPAD;
    const float2* z1 = z0 + NPAD;
    int km = (NPAD - k) & (NPAD-1);
    float2 a = z0[k], am = z0[km];
    float2 A0 = make_float2(0.5f*(a.x+am.x), 0.5f*(a.y-am.y));
    float2 R0 = make_float2(0.5f*(a.y+am.y), -0.5f*(a.x-am.x));
    float2 P0 = cxmul(A0,R0);
    float2 b = z1[k], bm = z1[km];
    float2 A1 = make_float2(0.5f*(b.x+bm.x), 0.5f*(b.y-bm.y));
    float2 R1 = make_float2(0.5f*(b.y+bm.y), -0.5f*(b.x-bm.x));
    float2 P1 = cxmul(A1,R1);
    const float s = 1.0f/65536.0f;
    Q[(size_t)p*NPAD + k] = make_float2((P0.x - P1.y)*s, (P0.y + P1.x)*s);
}

__global__ __launch_bounds__(256) void mfk_accum(const float2* __restrict__ U,
        const float* __restrict__ locraw, float* __restrict__ located,
        int g0, int eStart, int eCount, int bBase)
{
    int t = blockIdx.x*256 + threadIdx.x;   // < 32768
    int b = bBase + blockIdx.y;
    float sum = 0.f;
    for (int ei=0; ei<eCount; ei++){
        int cc = b*32 + eStart + ei;
        int lc = cc - g0;
        float2 u = U[(size_t)(lc>>1)*NPAD + t];
        float cv = (lc & 1) ? u.y : u.x;
        sum += cv + locraw[(size_t)lc*NSAMP + t];
    }
    located[(size_t)b*NSAMP + t] += sum;
}

__global__ __launch_bounds__(256) void mfk_drypack(const float* __restrict__ located,
        const float* __restrict__ rmA, const float* __restrict__ IR, float2* __restrict__ A)
{
    int t = blockIdx.x*256 + threadIdx.x;
    int b = blockIdx.y;
    float2 z = make_float2(0.f,0.f);
    if (t < NSAMP){
        float iv = 0.f;
        #pragma unroll
        for (int r=0;r<8;r++) iv += rmA[b*8+r]*IR[(size_t)r*NSAMP + t];
        z = make_float2(located[(size_t)b*NSAMP+t], iv);
    }
    A[(size_t)b*NPAD + t] = z;
}

__global__ __launch_bounds__(256) void mfk_final(const float2* __restrict__ U2,
        const float* __restrict__ located, const float* __restrict__ mxA, float* __restrict__ out)
{
    int t = blockIdx.x*256 + threadIdx.x;
    int b = blockIdx.y;
    float2 u = U2[(size_t)(b>>1)*NPAD + t];
    float wet = (b&1) ? u.y : u.x;
    float mx = mxA[b];
    out[(size_t)b*NSAMP + t] = located[(size_t)b*NSAMP+t]*(1.0f-mx) + wet*mx;
}

static float2* fft_run(float2* a, float2* b, int N, int batch, int dir, hipStream_t st)
{
    int Ns = 1;
    float2* src=a; float2* dst=b;
    for (int i=0;i<4;i++){
        int R = (N==NSAMP && i==3) ? 8 : 16;
        int T = N/R;
        dim3 g((T+255)/256, batch);
        if (R==16){
            if (dir<0) mfk_fft<16,-1><<<g,256,0,st>>>(src,dst,Ns,T);
            else       mfk_fft<16, 1><<<g,256,0,st>>>(src,dst,Ns,T);
        } else {
            if (dir<0) mfk_fft<8,-1><<<g,256,0,st>>>(src,dst,Ns,T);
            else       mfk_fft<8, 1><<<g,256,0,st>>>(src,dst,Ns,T);
        }
        Ns *= R;
        float2* t0=src; src=dst; dst=t0;
    }
    return src;   // result after 4 passes
}

extern "C" void kernel_launch(void* const* d_in, const int* in_sizes, int n_in,
                              void* d_out, int out_size, void* d_ws, size_t ws_size,
                              hipStream_t stream)
{
    (void)in_sizes; (void)n_in; (void)out_size;
    const float* EP   = (const float*)d_in[0];
    const float* MXR  = (const float*)d_in[1];
    const float* RL   = (const float*)d_in[2];
    const float* NOISE= (const float*)d_in[3];
    const float* IR   = (const float*)d_in[4];
    float* out = (float*)d_out;
    char* w = (char*)d_ws;

    // choose channels-per-group G to fit workspace
    auto need = [](long long g)->long long {
        return 2LL*g*NPAD*8 + 2LL*g*NSAMP*4 + (long long)NSAMP*8
             + 1LL*NCHAIN*128*4 + (128LL*8 + NCHAIN + 4 + 32 + 4LL*NSAMP)*4 + 16384;
    };
    int G = 128;
    while (G > 4 && need(G) > (long long)ws_size) G >>= 1;

    size_t off = 0;
    auto alloc = [&](size_t bytes)->char* {
        char* p = w + off; off += (bytes + 255) & ~(size_t)255; return p;
    };
    float2* arA    = (float2*)alloc((size_t)G*NPAD*8);
    float2* arB    = (float2*)alloc((size_t)G*NPAD*8);
    float*  locraw = (float*) alloc((size_t)G*NSAMP*4);
    float*  reson  = (float*) alloc((size_t)G*NSAMP*4);
    float2* nspec  = (float2*)alloc((size_t)NSAMP*8);
    float*  cum    = (float*) alloc((size_t)NCHAIN*128*4);
    float*  chP    = (float*) alloc(128*8*4);
    float*  chF    = (float*) alloc(NCHAIN*4);
    float*  mxA    = (float*) alloc(4*4);
    float*  rmA    = (float*) alloc(32*4);
    float*  located= (float*) alloc(4*NSAMP*4);

    (void)hipMemsetAsync(located, 0, 4*NSAMP*4, stream);
    mfk_setup<<<dim3(8),256,0,stream>>>(EP,MXR,RL,chP,chF,cum,mxA,rmA);

    // noise forward FFT (batch 1)
    mfk_r2c<<<dim3(128),256,0,stream>>>(NOISE, arA, NSAMP);
    float2* res = fft_run(arA, arB, NSAMP, 1, -1, stream);
    mfk_copy2<<<dim3(128),256,0,stream>>>(res, nspec, NSAMP);

    for (int g0 = 0; g0 < NCH; g0 += G){
        int P = G/2;
        mfk_specwin<<<dim3(128,P),256,0,stream>>>(nspec, chP, arA, g0);
        res = fft_run(arA, arB, NSAMP, P, +1, stream);            // -> arA
        mfk_unpack<<<dim3(128,P),256,0,stream>>>(res, chP, locraw, g0);
        mfk_reson<<<dim3(128,G),256,0,stream>>>(chF, cum, reson, g0);
        mfk_packZ<<<dim3(256,G),256,0,stream>>>(locraw, reson, arA);
        res = fft_run(arA, arB, NPAD, G, -1, stream);             // -> arA
        mfk_product<<<dim3(256,G/2),256,0,stream>>>(res, arB);
        res = fft_run(arB, arA, NPAD, G/2, +1, stream);           // -> arB
        int bBase, bCnt, eStart, eCount;
        if (G >= 32){ bBase = g0/32; bCnt = G/32; eStart = 0; eCount = 32; }
        else        { bBase = g0/32; bCnt = 1; eStart = g0 % 32; eCount = G; }
        mfk_accum<<<dim3(128,bCnt),256,0,stream>>>(res, locraw, located, g0, eStart, eCount, bBase);
    }

    // wet/dry stage
    mfk_drypack<<<dim3(256,4),256,0,stream>>>(located, rmA, IR, arA);
    res = fft_run(arA, arB, NPAD, 4, -1, stream);                 // -> arA
    mfk_product<<<dim3(256,2),256,0,stream>>>(res, arB);
    res = fft_run(arB, arA, NPAD, 2, +1, stream);                 // -> arB
    mfk_final<<<dim3(128,4),256,0,stream>>>(res, located, mxA, out);
}

// Round 3
// 328.439 us; speedup vs baseline: 1.2575x; 1.2575x over previous
//
#include <hip/hip_runtime.h>
#include <math.h>

#define NSAMP 32768
#define NPAD  65536
#define NCH   128
#define NCHAIN 2048

__device__ __forceinline__ float2 cxmul(float2 a, float2 b){
    return make_float2(a.x*b.x - a.y*b.y, a.x*b.y + a.y*b.x);
}

template<int DIR>
__device__ __forceinline__ void fft4v(float2* v, int i0, int i1, int i2, int i3){
    float2 a=v[i0], b=v[i1], c=v[i2], d=v[i3];
    float2 t0 = make_float2(a.x+c.x, a.y+c.y);
    float2 t1 = make_float2(a.x-c.x, a.y-c.y);
    float2 t2 = make_float2(b.x+d.x, b.y+d.y);
    float2 t3 = make_float2(b.x-d.x, b.y-d.y);
    v[i0] = make_float2(t0.x+t2.x, t0.y+t2.y);
    v[i2] = make_float2(t0.x-t2.x, t0.y-t2.y);
    if (DIR < 0) {
        v[i1] = make_float2(t1.x + t3.y, t1.y - t3.x);
        v[i3] = make_float2(t1.x - t3.y, t1.y + t3.x);
    } else {
        v[i1] = make_float2(t1.x - t3.y, t1.y + t3.x);
        v[i3] = make_float2(t1.x + t3.y, t1.y - t3.x);
    }
}

template<int DIR>
__device__ __forceinline__ void twm(float2& v, float c, float s){
    float sy = (DIR<0) ? -s : s;
    v = cxmul(v, make_float2(c, sy));
}

template<int DIR>
__device__ __forceinline__ void fft16r(float2* v){
    const float C1=0.92387953251128674f, S1=0.38268343236508978f, H=0.70710678118654752f;
    fft4v<DIR>(v,0,4,8,12);
    fft4v<DIR>(v,1,5,9,13);
    fft4v<DIR>(v,2,6,10,14);
    fft4v<DIR>(v,3,7,11,15);
    twm<DIR>(v[5],  C1, S1);
    twm<DIR>(v[6],  H,  H);
    twm<DIR>(v[7],  S1, C1);
    twm<DIR>(v[9],  H,  H);
    twm<DIR>(v[10], 0.0f, 1.0f);
    twm<DIR>(v[11], -H, H);
    twm<DIR>(v[13], S1, C1);
    twm<DIR>(v[14], -H, H);
    twm<DIR>(v[15], -C1, -S1);
    fft4v<DIR>(v,0,1,2,3);
    fft4v<DIR>(v,4,5,6,7);
    fft4v<DIR>(v,8,9,10,11);
    fft4v<DIR>(v,12,13,14,15);
    // X[r] at slot ((r&3)<<2)|(r>>2)
}

template<int DIR>
__device__ __forceinline__ void fft8r(float2* v){
    const float H=0.70710678118654752f;
    #pragma unroll
    for (int n1=0;n1<4;n1++){
        float2 t=v[n1], u=v[n1+4];
        v[n1]   = make_float2(t.x+u.x, t.y+u.y);
        v[n1+4] = make_float2(t.x-u.x, t.y-u.y);
    }
    twm<DIR>(v[5], H, H);
    twm<DIR>(v[6], 0.0f, 1.0f);
    twm<DIR>(v[7], -H, H);
    fft4v<DIR>(v,0,1,2,3);
    fft4v<DIR>(v,4,5,6,7);
    // X[r] at slot ((r&1)<<2)|(r>>1)
}

__device__ __forceinline__ int slot16(int r){ return ((r&3)<<2)|(r>>2); }
__device__ __forceinline__ int slot8(int r){ return ((r&1)<<2)|(r>>1); }

// ---------------- generic Stockham pass ----------------
template<int R, int DIR>
__global__ __launch_bounds__(256) void mfk_fft(const float2* __restrict__ src,
                                               float2* __restrict__ dst,
                                               int Ns, int T)
{
    int j = blockIdx.x*256 + threadIdx.x;
    if (j >= T) return;
    size_t aoff = (size_t)blockIdx.y * (size_t)T * (size_t)R;
    const float2* x = src + aoff;
    float2* y = dst + aoff;
    float2 v[R];
    #pragma unroll
    for (int r=0;r<R;r++) v[r] = x[j + r*T];
    int jm = j & (Ns-1);
    if (jm) {
        float base = (DIR<0 ? -6.2831853071795864f : 6.2831853071795864f)
                     * ((float)jm / (float)(Ns*R));
        #pragma unroll
        for (int r=1;r<R;r++){
            float s,c; __sincosf(base*(float)r, &s, &c);
            v[r] = cxmul(v[r], make_float2(c,s));
        }
    }
    if (R==16) fft16r<DIR>(v); else fft8r<DIR>(v);
    int idxD = (j & ~(Ns-1))*R + jm;
    float2* yo = y + idxD;
    #pragma unroll
    for (int r=0;r<R;r++){
        int slot = (R==16) ? slot16(r) : slot8(r);
        yo[r*Ns] = v[slot];
    }
}

// last NPAD inverse pass: store only lower half (t < 32768)
template<int DIR>
__global__ __launch_bounds__(256) void mfk_fftL_skip(const float2* __restrict__ src,
                                                     float2* __restrict__ dst, int T)
{
    const int Ns = 4096;
    int j = blockIdx.x*256 + threadIdx.x;
    if (j >= T) return;
    size_t aoff = (size_t)blockIdx.y * (size_t)T * 16;
    const float2* x = src + aoff;
    float2* y = dst + aoff;
    float2 v[16];
    #pragma unroll
    for (int r=0;r<16;r++) v[r] = x[j + r*T];
    int jm = j & (Ns-1);
    if (jm) {
        float base = (DIR<0 ? -6.2831853071795864f : 6.2831853071795864f)
                     * ((float)jm / (float)(Ns*16));
        #pragma unroll
        for (int r=1;r<16;r++){
            float s,c; __sincosf(base*(float)r, &s, &c);
            v[r] = cxmul(v[r], make_float2(c,s));
        }
    }
    fft16r<DIR>(v);
    float2* yo = y + j;   // idxD = j
    #pragma unroll
    for (int r=0;r<8;r++) yo[r*Ns] = v[slot16(r)];
}

// noise first pass: r2c fused (NSAMP, Ns=1, R=16, T=2048, batch 1)
__global__ __launch_bounds__(256) void mfk_noise_fft1(const float* __restrict__ noise,
                                                      float2* __restrict__ dst)
{
    int j = blockIdx.x*256 + threadIdx.x;   // < 2048
    float2 v[16];
    #pragma unroll
    for (int r=0;r<16;r++) v[r] = make_float2(noise[j + r*2048], 0.0f);
    fft16r<-1>(v);
    float2* yo = dst + j*16;
    #pragma unroll
    for (int r=0;r<16;r++) yo[r] = v[slot16(r)];
}

// first inverse-NSAMP pass with spectral window generation fused
__global__ __launch_bounds__(256) void mfk_specwin_fft1(const float2* __restrict__ nspec,
        const float* __restrict__ chP, float2* __restrict__ dst, int g0)
{
    int j = blockIdx.x*256 + threadIdx.x;   // < 2048
    int p = blockIdx.y;
    int c0 = g0 + 2*p;
    const float* A = chP + c0*8;
    const float* B = chP + (c0+1)*8;
    float a0=A[0], a1=A[1], a2=A[2], b0=B[0], b1=B[1], b2=B[2];
    float2 v[16];
    #pragma unroll
    for (int r=0;r<16;r++){
        int k = j + r*2048;
        int kw = (k <= 16384) ? k : (32768 - k);
        float rg = (float)kw * (1.0f/16384.0f);
        float t0 = (rg - a0)*a1;
        float w0 = expf(-0.5f*t0*t0)*a2;
        float t1 = (rg - b0)*b1;
        float w1 = expf(-0.5f*t1*t1)*b2;
        float2 N = nspec[k];
        v[r] = make_float2(N.x*w0 - N.y*w1, N.y*w0 + N.x*w1);
    }
    fft16r<1>(v);
    float2* yo = dst + (size_t)p*NSAMP + j*16;
    #pragma unroll
    for (int r=0;r<16;r++) yo[r] = v[slot16(r)];
}

// last inverse-NSAMP pass (R=8, Ns=4096) with time-window unpack fused
__global__ __launch_bounds__(256) void mfk_unpack_fftL(const float2* __restrict__ src,
        const float* __restrict__ chP, float* __restrict__ locraw, int g0)
{
    const int Ns = 4096, T = 4096;
    int j = blockIdx.x*256 + threadIdx.x;
    int p = blockIdx.y;
    const float2* x = src + (size_t)p*NSAMP;
    float2 v[8];
    #pragma unroll
    for (int r=0;r<8;r++) v[r] = x[j + r*T];
    int jm = j & (Ns-1);
    if (jm) {
        float base = 6.2831853071795864f * ((float)jm / (float)(Ns*8));
        #pragma unroll
        for (int r=1;r<8;r++){
            float s,c; __sincosf(base*(float)r, &s, &c);
            v[r] = cxmul(v[r], make_float2(c,s));
        }
    }
    fft8r<1>(v);
    int lc0 = 2*p;
    const float* C0 = chP + (g0+lc0)*8;
    const float* C1 = chP + (g0+lc0+1)*8;
    float c03=C0[3], c04=C0[4], c05=C0[5], c06=C0[6];
    float c13=C1[3], c14=C1[4], c15=C1[5], c16=C1[6];
    #pragma unroll
    for (int r=0;r<8;r++){
        int n = j + r*Ns;          // < 32768
        float2 val = v[slot8(r)];
        float rg = (float)((double)n * (1.0/32767.0));
        float tt0 = (rg - c03)*c04;
        float ew0 = expf(-0.5f*tt0*tt0)*c05;
        float tt1 = (rg - c13)*c14;
        float ew1 = expf(-0.5f*tt1*tt1)*c15;
        locraw[(size_t)lc0*NSAMP + n]     = val.x*(1.0f/32768.0f)*ew0*c06;
        locraw[(size_t)(lc0+1)*NSAMP + n] = val.y*(1.0f/32768.0f)*ew1*c16;
    }
}

// first forward-NPAD pass with packZ fused (upper half = implicit zeros)
__global__ __launch_bounds__(256) void mfk_packZ_fft1(const float* __restrict__ locraw,
        const float* __restrict__ reson, float2* __restrict__ dst)
{
    int j = blockIdx.x*256 + threadIdx.x;   // < 4096
    int lc = blockIdx.y;
    float2 v[16];
    #pragma unroll
    for (int r=0;r<8;r++){
        int idx = j + r*4096;
        v[r] = make_float2(locraw[(size_t)lc*NSAMP + idx], reson[(size_t)lc*NSAMP + idx]);
    }
    #pragma unroll
    for (int r=8;r<16;r++) v[r] = make_float2(0.f,0.f);
    fft16r<-1>(v);
    float2* yo = dst + (size_t)lc*NPAD + j*16;
    #pragma unroll
    for (int r=0;r<16;r++) yo[r] = v[slot16(r)];
}

// first inverse-NPAD pass with Hermitian product fused
__global__ __launch_bounds__(256) void mfk_prod_fft1(const float2* __restrict__ Z,
        float2* __restrict__ dst)
{
    int j = blockIdx.x*256 + threadIdx.x;   // < 4096
    int p = blockIdx.y;
    const float2* z0 = Z + (size_t)(2*p)*NPAD;
    const float2* z1 = z0 + NPAD;
    float2 v[16];
    #pragma unroll
    for (int r=0;r<16;r++){
        int k = j + r*4096;
        int km = (NPAD - k) & (NPAD-1);
        float2 a = z0[k], am = z0[km];
        float2 A0 = make_float2(0.5f*(a.x+am.x), 0.5f*(a.y-am.y));
        float2 R0 = make_float2(0.5f*(a.y+am.y), -0.5f*(a.x-am.x));
        float2 P0 = cxmul(A0,R0);
        float2 b = z1[k], bm = z1[km];
        float2 A1 = make_float2(0.5f*(b.x+bm.x), 0.5f*(b.y-bm.y));
        float2 R1 = make_float2(0.5f*(b.y+bm.y), -0.5f*(b.x-bm.x));
        float2 P1 = cxmul(A1,R1);
        const float s = 1.0f/65536.0f;
        v[r] = make_float2((P0.x - P1.y)*s, (P0.y + P1.x)*s);
    }
    fft16r<1>(v);
    float2* yo = dst + (size_t)p*NPAD + j*16;
    #pragma unroll
    for (int r=0;r<16;r++) yo[r] = v[slot16(r)];
}

// first forward-NPAD pass of wet chain: drypack fused
__global__ __launch_bounds__(256) void mfk_drypack_fft1(const float* __restrict__ located,
        const float* __restrict__ rmA, const float* __restrict__ IR, float2* __restrict__ dst)
{
    int j = blockIdx.x*256 + threadIdx.x;   // < 4096
    int b = blockIdx.y;
    float rm[8];
    #pragma unroll
    for (int r=0;r<8;r++) rm[r] = rmA[b*8+r];
    float2 v[16];
    #pragma unroll
    for (int r=0;r<8;r++){
        int idx = j + r*4096;
        float iv = 0.f;
        #pragma unroll
        for (int q=0;q<8;q++) iv += rm[q]*IR[(size_t)q*NSAMP + idx];
        v[r] = make_float2(located[(size_t)b*NSAMP + idx], iv);
    }
    #pragma unroll
    for (int r=8;r<16;r++) v[r] = make_float2(0.f,0.f);
    fft16r<-1>(v);
    float2* yo = dst + (size_t)b*NPAD + j*16;
    #pragma unroll
    for (int r=0;r<16;r++) yo[r] = v[slot16(r)];
}

// last inverse-NPAD pass of wet chain: final mix fused, writes out
__global__ __launch_bounds__(256) void mfk_final_fftL(const float2* __restrict__ src,
        const float* __restrict__ located, const float* __restrict__ mxA,
        float* __restrict__ out)
{
    const int Ns = 4096, T = 4096;
    int j = blockIdx.x*256 + threadIdx.x;
    int p = blockIdx.y;       // pair: batches 2p, 2p+1
    const float2* x = src + (size_t)p*NPAD;
    float2 v[16];
    #pragma unroll
    for (int r=0;r<16;r++) v[r] = x[j + r*T];
    int jm = j & (Ns-1);
    if (jm) {
        float base = 6.2831853071795864f * ((float)jm / (float)(Ns*16));
        #pragma unroll
        for (int r=1;r<16;r++){
            float s,c; __sincosf(base*(float)r, &s, &c);
            v[r] = cxmul(v[r], make_float2(c,s));
        }
    }
    fft16r<1>(v);
    int b0 = 2*p, b1 = 2*p+1;
    float mx0 = mxA[b0], mx1 = mxA[b1];
    #pragma unroll
    for (int r=0;r<8;r++){
        int t = j + r*Ns;     // < 32768
        float2 val = v[slot16(r)];
        out[(size_t)b0*NSAMP + t] = located[(size_t)b0*NSAMP+t]*(1.0f-mx0) + val.x*mx0;
        out[(size_t)b1*NSAMP + t] = located[(size_t)b1*NSAMP+t]*(1.0f-mx1) + val.y*mx1;
    }
}

// ---------------- setup ----------------
__global__ __launch_bounds__(256) void mfk_setup(const float* __restrict__ EP, const float* __restrict__ MXR,
        const float* __restrict__ RL, float* __restrict__ chP,
        unsigned* __restrict__ chQm, unsigned* __restrict__ chQs, float* __restrict__ chQsc,
        float* __restrict__ cum,
        float* __restrict__ mxA, float* __restrict__ rmA)
{
    int q = blockIdx.x*256 + threadIdx.x;
    if (q >= NCHAIN) return;
    int c = q >> 4, h = q & 15;
    const float* P = EP + c*22;
    const float MINF = (float)(20.0/11025.0);
    const float DRF  = (float)(4000.0/11025.0 - 20.0/11025.0);
    const float LSQ  = (float)0.9189385332046727;
    float f0m = __fmul_rn(P[4], P[4]);
    float f0s = __fadd_rn(MINF, __fmul_rn(f0m, DRF));
    float fr  = __fmul_rn(f0s, (float)(h+1));
    if (fr >= 1.0f) fr = 0.0f;
    // exact rational decomposition fr = m24 * 2^-s
    int e; float mant = frexpf(fr, &e);
    unsigned m24 = (unsigned)(mant * 16777216.0f);
    int s = 24 - e;
    if (fr == 0.0f){ m24 = 0u; s = 24; }
    chQm[q] = m24;
    chQs[q] = (unsigned)s;
    chQsc[q] = ldexpf(2.0f, -s);   // scale so sinpif(bits*scale) = sin(2*pi*frac)
    // cumprod of res
    float rs = __fadd_rn(__fmul_rn(P[6+h], 0.2f), 0.8f);
    float cp = rs;
    float* crow = cum + (size_t)q*128;
    for (int j=0;j<128;j++){ crow[j] = cp; cp = __fmul_rn(cp, rs); }
    if (h == 0) {
        float fm  = __fmul_rn(P[0],P[0]);
        float fmu = __fadd_rn(MINF, __fmul_rn(fm, DRF));
        float fsg = 1e-8f + P[1]*0.1f;
        float fsi = 1.0f/fsg;
        int i0 = (int)floorf(fmu*16384.0f + 0.5f);
        i0 = min(max(i0,0),16384);
        float rg = (float)i0 * (1.0f/16384.0f);
        float tt = (rg - fmu)*fsi;
        float Lc = logf(fsg) + LSQ;
        float sc = expf(-Lc) / (expf(-0.5f*tt*tt - Lc) + 1e-8f);
        float tmu = P[2];
        float tsg = 1e-8f + P[3]*0.1f;
        float tsi = 1.0f/tsg;
        int i1 = (int)floorf(tmu*32767.0f + 0.5f);
        i1 = min(max(i1,0),32767);
        float rg1 = (float)((double)i1 * (1.0/32767.0));
        float tt1 = (rg1 - tmu)*tsi;
        float Lc1 = logf(tsg) + LSQ;
        float sc1 = expf(-Lc1) / (expf(-0.5f*tt1*tt1 - Lc1) + 1e-8f);
        float amp = P[5]*P[5];
        float* o = chP + c*8;
        o[0]=fmu; o[1]=fsi; o[2]=sc; o[3]=tmu; o[4]=tsi; o[5]=sc1; o[6]=amp; o[7]=0.f;
    }
    if (q < 4) {
        int b = q;
        mxA[b] = 1.0f/(1.0f + expf(-MXR[b]));
        const float* rl = RL + b*8;
        float mx = rl[0];
        for (int r=1;r<8;r++) mx = fmaxf(mx, rl[r]);
        float sum=0.f;
        float e2[8];
        for (int r=0;r<8;r++){ e2[r]=expf(rl[r]-mx); sum+=e2[r]; }
        for (int r=0;r<8;r++) rmA[b*8+r] = e2[r]/sum;
    }
}

// ---------------- resonances (integer-exact phase) ----------------
__global__ __launch_bounds__(256) void mfk_reson(const unsigned* __restrict__ chQm,
        const unsigned* __restrict__ chQs, const float* __restrict__ chQsc,
        const float* __restrict__ cum, float* __restrict__ reson, int g0)
{
    __shared__ float cp3[16][4];
    __shared__ unsigned qm[16];
    __shared__ unsigned qs[16];
    __shared__ float qsc[16];
    int j  = blockIdx.x;          // frame block 0..127
    int lc = blockIdx.y;
    int cg = g0 + lc;
    int tid = threadIdx.x;
    int base = max(j-1, 0);
    if (tid < 16) {
        int q = cg*16 + tid;
        qm[tid] = chQm[q];
        qs[tid] = chQs[q];
        qsc[tid] = chQsc[q];
        const float* crow = cum + (size_t)q*128;
        cp3[tid][0] = crow[min(base+0,127)];
        cp3[tid][1] = crow[min(base+1,127)];
        cp3[tid][2] = crow[min(base+2,127)];
    }
    __syncthreads();
    int t = j*256 + tid;
    float co = ((float)t + 0.5f)*0.00390625f - 0.5f;
    co = fminf(fmaxf(co, 0.0f), 127.0f);
    int lo = (int)floorf(co);
    float w = co - (float)lo;
    int s0 = lo - base;
    int s1 = min(lo+1, 127) - base;
    unsigned T1 = (unsigned)(t+1);
    float acc = 0.0f;
    #pragma unroll
    for (int hh=0; hh<16; hh++){
        float env = cp3[hh][s0]*(1.0f-w) + cp3[hh][s1]*w;
        unsigned m = qm[hh];
        unsigned s = qs[hh];
        unsigned plo = m * T1;
        unsigned phi = __umulhi(m, T1);
        unsigned lo_m, hi_m;
        if (s >= 32u){ lo_m = plo; hi_m = phi & ((1u<<(s-32u))-1u); }
        else         { lo_m = plo & ((1u<<s)-1u); hi_m = 0u; }
        float fb = fmaf((float)hi_m, 4294967296.0f, (float)lo_m);
        acc += env * sinpif(fb * qsc[hh]);
    }
    reson[(size_t)lc*NSAMP + t] = acc;
}

// ---------------- accumulate events into located ----------------
__global__ __launch_bounds__(256) void mfk_accum(const float2* __restrict__ U,
        const float* __restrict__ locraw, float* __restrict__ located,
        int g0, int eStart, int eCount, int bBase)
{
    int t = blockIdx.x*256 + threadIdx.x;
    int b = bBase + blockIdx.y;
    float sum = 0.f;
    for (int ei=0; ei<eCount; ei++){
        int cc = b*32 + eStart + ei;
        int lc = cc - g0;
        float2 u = U[(size_t)(lc>>1)*NPAD + t];
        float cv = (lc & 1) ? u.y : u.x;
        sum += cv + locraw[(size_t)lc*NSAMP + t];
    }
    located[(size_t)b*NSAMP + t] += sum;
}

extern "C" void kernel_launch(void* const* d_in, const int* in_sizes, int n_in,
                              void* d_out, int out_size, void* d_ws, size_t ws_size,
                              hipStream_t stream)
{
    (void)in_sizes; (void)n_in; (void)out_size;
    const float* EP   = (const float*)d_in[0];
    const float* MXR  = (const float*)d_in[1];
    const float* RL   = (const float*)d_in[2];
    const float* NOISE= (const float*)d_in[3];
    const float* IR   = (const float*)d_in[4];
    float* out = (float*)d_out;
    char* w = (char*)d_ws;

    auto need = [](long long g)->long long {
        return 2LL*g*NPAD*8 + 2LL*g*NSAMP*4 + (long long)NSAMP*8
             + 1LL*NCHAIN*128*4 + (128LL*8 + 3LL*NCHAIN + 4 + 32 + 4LL*NSAMP)*4 + 16384;
    };
    int G = 128;
    while (G > 4 && need(G) > (long long)ws_size) G >>= 1;

    size_t off = 0;
    auto alloc = [&](size_t bytes)->char* {
        char* p = w + off; off += (bytes + 255) & ~(size_t)255; return p;
    };
    float2*   arA    = (float2*)alloc((size_t)G*NPAD*8);
    float2*   arB    = (float2*)alloc((size_t)G*NPAD*8);
    float*    locraw = (float*) alloc((size_t)G*NSAMP*4);
    float*    reson  = (float*) alloc((size_t)G*NSAMP*4);
    float2*   nspec  = (float2*)alloc((size_t)NSAMP*8);
    float*    cum    = (float*) alloc((size_t)NCHAIN*128*4);
    float*    chP    = (float*) alloc(128*8*4);
    unsigned* chQm   = (unsigned*)alloc(NCHAIN*4);
    unsigned* chQs   = (unsigned*)alloc(NCHAIN*4);
    float*    chQsc  = (float*) alloc(NCHAIN*4);
    float*    mxA    = (float*) alloc(4*4);
    float*    rmA    = (float*) alloc(32*4);
    float*    located= (float*) alloc(4*NSAMP*4);

    (void)hipMemsetAsync(located, 0, 4*NSAMP*4, stream);
    mfk_setup<<<dim3(8),256,0,stream>>>(EP,MXR,RL,chP,chQm,chQs,chQsc,cum,mxA,rmA);

    // noise forward FFT (batch 1): NOISE -> nspec
    mfk_noise_fft1<<<dim3(8),256,0,stream>>>(NOISE, arB);
    mfk_fft<16,-1><<<dim3(8,1),256,0,stream>>>(arB, arA, 16,   2048);
    mfk_fft<16,-1><<<dim3(8,1),256,0,stream>>>(arA, arB, 256,  2048);
    mfk_fft<8, -1><<<dim3(16,1),256,0,stream>>>(arB, nspec, 4096, 4096);

    for (int g0 = 0; g0 < NCH; g0 += G){
        int P = G/2;
        // inverse NSAMP (windowed noise spectrum -> locraw)
        mfk_specwin_fft1<<<dim3(8,P),256,0,stream>>>(nspec, chP, arA, g0);
        mfk_fft<16,1><<<dim3(8,P),256,0,stream>>>(arA, arB, 16,  2048);
        mfk_fft<16,1><<<dim3(8,P),256,0,stream>>>(arB, arA, 256, 2048);
        mfk_unpack_fftL<<<dim3(16,P),256,0,stream>>>(arA, chP, locraw, g0);
        // resonances
        mfk_reson<<<dim3(128,G),256,0,stream>>>(chQm, chQs, chQsc, cum, reson, g0);
        // forward NPAD (packed located + i*reson)
        mfk_packZ_fft1<<<dim3(16,G),256,0,stream>>>(locraw, reson, arA);
        mfk_fft<16,-1><<<dim3(16,G),256,0,stream>>>(arA, arB, 16,   4096);
        mfk_fft<16,-1><<<dim3(16,G),256,0,stream>>>(arB, arA, 256,  4096);
        mfk_fft<16,-1><<<dim3(16,G),256,0,stream>>>(arA, arB, 4096, 4096);
        // inverse NPAD with product fused
        mfk_prod_fft1<<<dim3(16,P),256,0,stream>>>(arB, arA);
        mfk_fft<16,1><<<dim3(16,P),256,0,stream>>>(arA, arB, 16,  4096);
        mfk_fft<16,1><<<dim3(16,P),256,0,stream>>>(arB, arA, 256, 4096);
        mfk_fftL_skip<1><<<dim3(16,P),256,0,stream>>>(arA, arB, 4096);
        int bBase, bCnt, eStart, eCount;
        if (G >= 32){ bBase = g0/32; bCnt = G/32; eStart = 0; eCount = 32; }
        else        { bBase = g0/32; bCnt = 1; eStart = g0 % 32; eCount = G; }
        mfk_accum<<<dim3(128,bCnt),256,0,stream>>>(arB, locraw, located, g0, eStart, eCount, bBase);
    }

    // wet/dry chain (batch 4 -> 2 pairs)
    mfk_drypack_fft1<<<dim3(16,4),256,0,stream>>>(located, rmA, IR, arA);
    mfk_fft<16,-1><<<dim3(16,4),256,0,stream>>>(arA, arB, 16,   4096);
    mfk_fft<16,-1><<<dim3(16,4),256,0,stream>>>(arB, arA, 256,  4096);
    mfk_fft<16,-1><<<dim3(16,4),256,0,stream>>>(arA, arB, 4096, 4096);
    mfk_prod_fft1<<<dim3(16,2),256,0,stream>>>(arB, arA);
    mfk_fft<16,1><<<dim3(16,2),256,0,stream>>>(arA, arB, 16,  4096);
    mfk_fft<16,1><<<dim3(16,2),256,0,stream>>>(arB, arA, 256, 4096);
    mfk_final_fftL<<<dim3(16,2),256,0,stream>>>(arA, located, mxA, out);
}

// Round 4
// 201.929 us; speedup vs baseline: 2.0454x; 1.6265x over previous
//
#include <hip/hip_runtime.h>
#include <math.h>

#define NSAMP 32768
#define NPAD  65536
#define NCH   128
#define NCHAIN 2048
#define TWO_PI 6.2831853071795864f

__device__ __forceinline__ float2 cxmul(float2 a, float2 b){
    return make_float2(a.x*b.x - a.y*b.y, a.x*b.y + a.y*b.x);
}

template<int DIR>
__device__ __forceinline__ void fft4v(float2* v, int i0, int i1, int i2, int i3){
    float2 a=v[i0], b=v[i1], c=v[i2], d=v[i3];
    float2 t0 = make_float2(a.x+c.x, a.y+c.y);
    float2 t1 = make_float2(a.x-c.x, a.y-c.y);
    float2 t2 = make_float2(b.x+d.x, b.y+d.y);
    float2 t3 = make_float2(b.x-d.x, b.y-d.y);
    v[i0] = make_float2(t0.x+t2.x, t0.y+t2.y);
    v[i2] = make_float2(t0.x-t2.x, t0.y-t2.y);
    if (DIR < 0) {
        v[i1] = make_float2(t1.x + t3.y, t1.y - t3.x);
        v[i3] = make_float2(t1.x - t3.y, t1.y + t3.x);
    } else {
        v[i1] = make_float2(t1.x - t3.y, t1.y + t3.x);
        v[i3] = make_float2(t1.x + t3.y, t1.y - t3.x);
    }
}

template<int DIR>
__device__ __forceinline__ void twm(float2& v, float c, float s){
    float sy = (DIR<0) ? -s : s;
    v = cxmul(v, make_float2(c, sy));
}

template<int DIR>
__device__ __forceinline__ void fft16r(float2* v){
    const float C1=0.92387953251128674f, S1=0.38268343236508978f, H=0.70710678118654752f;
    fft4v<DIR>(v,0,4,8,12);
    fft4v<DIR>(v,1,5,9,13);
    fft4v<DIR>(v,2,6,10,14);
    fft4v<DIR>(v,3,7,11,15);
    twm<DIR>(v[5],  C1, S1);
    twm<DIR>(v[6],  H,  H);
    twm<DIR>(v[7],  S1, C1);
    twm<DIR>(v[9],  H,  H);
    twm<DIR>(v[10], 0.0f, 1.0f);
    twm<DIR>(v[11], -H, H);
    twm<DIR>(v[13], S1, C1);
    twm<DIR>(v[14], -H, H);
    twm<DIR>(v[15], -C1, -S1);
    fft4v<DIR>(v,0,1,2,3);
    fft4v<DIR>(v,4,5,6,7);
    fft4v<DIR>(v,8,9,10,11);
    fft4v<DIR>(v,12,13,14,15);
    // X[r] at slot ((r&3)<<2)|(r>>2)
}

template<int DIR>
__device__ __forceinline__ void fft8r(float2* v){
    const float H=0.70710678118654752f;
    #pragma unroll
    for (int n1=0;n1<4;n1++){
        float2 t=v[n1], u=v[n1+4];
        v[n1]   = make_float2(t.x+u.x, t.y+u.y);
        v[n1+4] = make_float2(t.x-u.x, t.y-u.y);
    }
    twm<DIR>(v[5], H, H);
    twm<DIR>(v[6], 0.0f, 1.0f);
    twm<DIR>(v[7], -H, H);
    fft4v<DIR>(v,0,1,2,3);
    fft4v<DIR>(v,4,5,6,7);
    // X[r] at slot ((r&1)<<2)|(r>>1)
}

__device__ __forceinline__ int slot16(int r){ return ((r&3)<<2)|(r>>2); }
__device__ __forceinline__ int slot8(int r){ return ((r&1)<<2)|(r>>1); }
__device__ __forceinline__ int lpad(int l){ return l + (l>>4); }

// ---------------- generic Stockham pass (NSAMP + noise chains) ----------------
template<int R, int DIR>
__global__ __launch_bounds__(256) void mfk_fft(const float2* __restrict__ src,
                                               float2* __restrict__ dst,
                                               int Ns, int T)
{
    int j = blockIdx.x*256 + threadIdx.x;
    if (j >= T) return;
    size_t aoff = (size_t)blockIdx.y * (size_t)T * (size_t)R;
    const float2* x = src + aoff;
    float2* y = dst + aoff;
    float2 v[R];
    #pragma unroll
    for (int r=0;r<R;r++) v[r] = x[j + r*T];
    int jm = j & (Ns-1);
    if (jm) {
        float base = (DIR<0 ? -TWO_PI : TWO_PI) * ((float)jm / (float)(Ns*R));
        #pragma unroll
        for (int r=1;r<R;r++){
            float s,c; __sincosf(base*(float)r, &s, &c);
            v[r] = cxmul(v[r], make_float2(c,s));
        }
    }
    if (R==16) fft16r<DIR>(v); else fft8r<DIR>(v);
    int idxD = (j & ~(Ns-1))*R + jm;
    float2* yo = y + idxD;
    #pragma unroll
    for (int r=0;r<R;r++){
        int slot = (R==16) ? slot16(r) : slot8(r);
        yo[r*Ns] = v[slot];
    }
}

// noise first pass: r2c fused
__global__ __launch_bounds__(256) void mfk_noise_fft1(const float* __restrict__ noise,
                                                      float2* __restrict__ dst)
{
    int j = blockIdx.x*256 + threadIdx.x;   // < 2048
    float2 v[16];
    #pragma unroll
    for (int r=0;r<16;r++) v[r] = make_float2(noise[j + r*2048], 0.0f);
    fft16r<-1>(v);
    float2* yo = dst + j*16;
    #pragma unroll
    for (int r=0;r<16;r++) yo[r] = v[slot16(r)];
}

// first inverse-NSAMP pass with spectral window fused
__global__ __launch_bounds__(256) void mfk_specwin_fft1(const float2* __restrict__ nspec,
        const float* __restrict__ chP, float2* __restrict__ dst, int g0)
{
    int j = blockIdx.x*256 + threadIdx.x;   // < 2048
    int p = blockIdx.y;
    int c0 = g0 + 2*p;
    const float* A = chP + c0*8;
    const float* B = chP + (c0+1)*8;
    float a0=A[0], a1=A[1], a2=A[2], b0=B[0], b1=B[1], b2=B[2];
    float2 v[16];
    #pragma unroll
    for (int r=0;r<16;r++){
        int k = j + r*2048;
        int kw = (k <= 16384) ? k : (32768 - k);
        float rg = (float)kw * (1.0f/16384.0f);
        float t0 = (rg - a0)*a1;
        float w0 = expf(-0.5f*t0*t0)*a2;
        float t1 = (rg - b0)*b1;
        float w1 = expf(-0.5f*t1*t1)*b2;
        float2 N = nspec[k];
        v[r] = make_float2(N.x*w0 - N.y*w1, N.y*w0 + N.x*w1);
    }
    fft16r<1>(v);
    float2* yo = dst + (size_t)p*NSAMP + j*16;
    #pragma unroll
    for (int r=0;r<16;r++) yo[r] = v[slot16(r)];
}

// last inverse-NSAMP pass (R=8, Ns=4096) with time-window unpack fused
__global__ __launch_bounds__(256) void mfk_unpack_fftL(const float2* __restrict__ src,
        const float* __restrict__ chP, float* __restrict__ locraw, int g0)
{
    const int Ns = 4096, T = 4096;
    int j = blockIdx.x*256 + threadIdx.x;
    int p = blockIdx.y;
    const float2* x = src + (size_t)p*NSAMP;
    float2 v[8];
    #pragma unroll
    for (int r=0;r<8;r++) v[r] = x[j + r*T];
    int jm = j & (Ns-1);
    if (jm) {
        float base = TWO_PI * ((float)jm / (float)(Ns*8));
        #pragma unroll
        for (int r=1;r<8;r++){
            float s,c; __sincosf(base*(float)r, &s, &c);
            v[r] = cxmul(v[r], make_float2(c,s));
        }
    }
    fft8r<1>(v);
    int lc0 = 2*p;
    const float* C0 = chP + (g0+lc0)*8;
    const float* C1 = chP + (g0+lc0+1)*8;
    float c03=C0[3], c04=C0[4], c05=C0[5], c06=C0[6];
    float c13=C1[3], c14=C1[4], c15=C1[5], c16=C1[6];
    #pragma unroll
    for (int r=0;r<8;r++){
        int n = j + r*Ns;
        float2 val = v[slot8(r)];
        float rg = (float)((double)n * (1.0/32767.0));
        float tt0 = (rg - c03)*c04;
        float ew0 = expf(-0.5f*tt0*tt0)*c05;
        float tt1 = (rg - c13)*c14;
        float ew1 = expf(-0.5f*tt1*tt1)*c15;
        locraw[(size_t)lc0*NSAMP + n]     = val.x*(1.0f/32768.0f)*ew0*c06;
        locraw[(size_t)(lc0+1)*NSAMP + n] = val.y*(1.0f/32768.0f)*ew1*c16;
    }
}

// ---------------- fused double-stage NPAD kernels ----------------
// Stages (Ns=1,16): thread t of block p covers stage-A j = 256*(t>>4)+16*p+(t&15);
// LDS holds the 4096-elem intersection; stage-B j2 = 256*p + t.
template<int DIR>
__device__ __forceinline__ void fuse01_tail(float2 (&v)[16], float2* lds, int t, int p,
                                            float2* __restrict__ outB)
{
    fft16r<DIR>(v);                       // stage A, Ns=1: no twiddle
    int r2 = t>>4, w = t&15;
    #pragma unroll
    for (int r=0;r<16;r++) lds[lpad(256*r2 + 16*w + r)] = v[slot16(r)];
    __syncthreads();
    #pragma unroll
    for (int q=0;q<16;q++) v[q] = lds[lpad(256*q + t)];
    int j2 = 256*p + t;
    int jm = t & 15;
    if (jm){
        float base = (DIR<0?-TWO_PI:TWO_PI) * ((float)jm * (1.0f/256.0f));
        #pragma unroll
        for (int r=1;r<16;r++){ float s,c; __sincosf(base*(float)r,&s,&c); v[r]=cxmul(v[r],make_float2(c,s)); }
    }
    fft16r<DIR>(v);
    float2* yo = outB + (j2>>4)*256 + (j2&15);
    #pragma unroll
    for (int r=0;r<16;r++) yo[16*r] = v[slot16(r)];
}

// fwd NPAD first pair, packZ fused (upper half implicit zeros)
__global__ __launch_bounds__(256) void mfk_packZ_f01(const float* __restrict__ locraw,
        const float* __restrict__ reson, float2* __restrict__ dst)
{
    __shared__ float2 lds[4352];
    int t = threadIdx.x, p = blockIdx.x, lc = blockIdx.y;
    int j = 256*(t>>4) + 16*p + (t&15);
    const float* la = locraw + (size_t)lc*NSAMP;
    const float* ra = reson  + (size_t)lc*NSAMP;
    float2 v[16];
    #pragma unroll
    for (int r=0;r<8;r++){ int n = j + 4096*r; v[r] = make_float2(la[n], ra[n]); }
    #pragma unroll
    for (int r=8;r<16;r++) v[r] = make_float2(0.f,0.f);
    fuse01_tail<-1>(v, lds, t, p, dst + (size_t)lc*NPAD);
}

// inverse NPAD first pair, Hermitian product fused
__global__ __launch_bounds__(256) void mfk_prod_f01(const float2* __restrict__ Z,
        float2* __restrict__ dst)
{
    __shared__ float2 lds[4352];
    int t = threadIdx.x, p = blockIdx.x, pr = blockIdx.y;
    const float2* z0 = Z + (size_t)(2*pr)*NPAD;
    const float2* z1 = z0 + NPAD;
    int j = 256*(t>>4) + 16*p + (t&15);
    float2 v[16];
    #pragma unroll
    for (int r=0;r<16;r++){
        int k = j + 4096*r;
        int km = (NPAD - k) & (NPAD-1);
        float2 a = z0[k], am = z0[km];
        float2 A0 = make_float2(0.5f*(a.x+am.x), 0.5f*(a.y-am.y));
        float2 R0 = make_float2(0.5f*(a.y+am.y), -0.5f*(a.x-am.x));
        float2 P0 = cxmul(A0,R0);
        float2 b = z1[k], bm = z1[km];
        float2 A1 = make_float2(0.5f*(b.x+bm.x), 0.5f*(b.y-bm.y));
        float2 R1 = make_float2(0.5f*(b.y+bm.y), -0.5f*(b.x-bm.x));
        float2 P1 = cxmul(A1,R1);
        const float s = 1.0f/65536.0f;
        v[r] = make_float2((P0.x - P1.y)*s, (P0.y + P1.x)*s);
    }
    fuse01_tail<1>(v, lds, t, p, dst + (size_t)pr*NPAD);
}

// wet chain first pair, drypack fused
__global__ __launch_bounds__(256) void mfk_dry_f01(const float* __restrict__ located,
        const float* __restrict__ rmA, const float* __restrict__ IR, float2* __restrict__ dst)
{
    __shared__ float2 lds[4352];
    int t = threadIdx.x, p = blockIdx.x, b = blockIdx.y;
    int j = 256*(t>>4) + 16*p + (t&15);
    float rm[8];
    #pragma unroll
    for (int r=0;r<8;r++) rm[r] = rmA[b*8+r];
    float2 v[16];
    #pragma unroll
    for (int r=0;r<8;r++){
        int n = j + 4096*r;
        float iv = 0.f;
        #pragma unroll
        for (int q=0;q<8;q++) iv += rm[q]*IR[(size_t)q*NSAMP + n];
        v[r] = make_float2(located[(size_t)b*NSAMP + n], iv);
    }
    #pragma unroll
    for (int r=8;r<16;r++) v[r] = make_float2(0.f,0.f);
    fuse01_tail<-1>(v, lds, t, p, dst + (size_t)b*NPAD);
}

// Stages (Ns=256,4096). Same thread->j map; different LDS layout + twiddles.
template<int DIR, int NSTORE>
__global__ __launch_bounds__(256) void mfk_f23(const float2* __restrict__ src,
                                               float2* __restrict__ dst)
{
    __shared__ float2 lds[4352];
    int t = threadIdx.x, p = blockIdx.x;
    size_t boff = (size_t)blockIdx.y * NPAD;
    int a = t>>4, w = t&15;
    int j = 256*a + 16*p + w;
    const float2* x = src + boff;
    float2 v[16];
    #pragma unroll
    for (int r=0;r<16;r++) v[r] = x[j + 4096*r];
    int jm = 16*p + w;                    // j mod 256
    if (jm){
        float base = (DIR<0?-TWO_PI:TWO_PI)*((float)jm*(1.0f/4096.0f));
        #pragma unroll
        for (int r=1;r<16;r++){ float s,c; __sincosf(base*(float)r,&s,&c); v[r]=cxmul(v[r],make_float2(c,s)); }
    }
    fft16r<DIR>(v);
    #pragma unroll
    for (int r=0;r<16;r++) lds[lpad(256*a + 16*r + w)] = v[slot16(r)];
    __syncthreads();
    #pragma unroll
    for (int q=0;q<16;q++) v[q] = lds[lpad(256*q + t)];
    {
        float base = (DIR<0?-TWO_PI:TWO_PI)*((float)j*(1.0f/65536.0f));
        #pragma unroll
        for (int r=1;r<16;r++){ float s,c; __sincosf(base*(float)r,&s,&c); v[r]=cxmul(v[r],make_float2(c,s)); }
    }
    fft16r<DIR>(v);
    float2* yo = dst + boff + j;
    #pragma unroll
    for (int r=0;r<NSTORE;r++) yo[4096*r] = v[slot16(r)];
}

// wet chain last pair: final mix fused, writes out
__global__ __launch_bounds__(256) void mfk_f23_final(const float2* __restrict__ src,
        const float* __restrict__ located, const float* __restrict__ mxA,
        float* __restrict__ out)
{
    __shared__ float2 lds[4352];
    int t = threadIdx.x, p = blockIdx.x;
    size_t boff = (size_t)blockIdx.y * NPAD;
    int a = t>>4, w = t&15;
    int j = 256*a + 16*p + w;
    const float2* x = src + boff;
    float2 v[16];
    #pragma unroll
    for (int r=0;r<16;r++) v[r] = x[j + 4096*r];
    int jm = 16*p + w;
    if (jm){
        float base = TWO_PI*((float)jm*(1.0f/4096.0f));
        #pragma unroll
        for (int r=1;r<16;r++){ float s,c; __sincosf(base*(float)r,&s,&c); v[r]=cxmul(v[r],make_float2(c,s)); }
    }
    fft16r<1>(v);
    #pragma unroll
    for (int r=0;r<16;r++) lds[lpad(256*a + 16*r + w)] = v[slot16(r)];
    __syncthreads();
    #pragma unroll
    for (int q=0;q<16;q++) v[q] = lds[lpad(256*q + t)];
    {
        float base = TWO_PI*((float)j*(1.0f/65536.0f));
        #pragma unroll
        for (int r=1;r<16;r++){ float s,c; __sincosf(base*(float)r,&s,&c); v[r]=cxmul(v[r],make_float2(c,s)); }
    }
    fft16r<1>(v);
    int b0 = 2*blockIdx.y, b1 = b0+1;
    float mx0 = mxA[b0], mx1 = mxA[b1];
    #pragma unroll
    for (int r=0;r<8;r++){
        int ts = j + 4096*r;
        float2 val = v[slot16(r)];
        out[(size_t)b0*NSAMP+ts] = located[(size_t)b0*NSAMP+ts]*(1.f-mx0) + val.x*mx0;
        out[(size_t)b1*NSAMP+ts] = located[(size_t)b1*NSAMP+ts]*(1.f-mx1) + val.y*mx1;
    }
}

// ---------------- setup ----------------
__global__ __launch_bounds__(256) void mfk_setup(const float* __restrict__ EP, const float* __restrict__ MXR,
        const float* __restrict__ RL, float* __restrict__ chP,
        unsigned* __restrict__ chQ, float* __restrict__ cum,
        float* __restrict__ mxA, float* __restrict__ rmA)
{
    int q = blockIdx.x*256 + threadIdx.x;
    if (q >= NCHAIN) return;
    int c = q >> 4, h = q & 15;
    const float* P = EP + c*22;
    const float MINF = (float)(20.0/11025.0);
    const float DRF  = (float)(4000.0/11025.0 - 20.0/11025.0);
    const float LSQ  = (float)0.9189385332046727;
    float f0m = __fmul_rn(P[4], P[4]);
    float f0s = __fadd_rn(MINF, __fmul_rn(f0m, DRF));
    float fr  = __fmul_rn(f0s, (float)(h+1));
    if (fr >= 1.0f) fr = 0.0f;
    // Q32 fixed-point frequency (revolutions/sample * 2^32), error <= 2^-33 rev/sample
    double fd = (double)fr * 4294967296.0;
    chQ[q] = (unsigned)(unsigned long long)(fd + 0.5);
    // cumprod of res (sequential f32)
    float rs = __fadd_rn(__fmul_rn(P[6+h], 0.2f), 0.8f);
    float cp = rs;
    float* crow = cum + (size_t)q*128;
    for (int j=0;j<128;j++){ crow[j] = cp; cp = __fmul_rn(cp, rs); }
    if (h == 0) {
        float fm  = __fmul_rn(P[0],P[0]);
        float fmu = __fadd_rn(MINF, __fmul_rn(fm, DRF));
        float fsg = 1e-8f + P[1]*0.1f;
        float fsi = 1.0f/fsg;
        int i0 = (int)floorf(fmu*16384.0f + 0.5f);
        i0 = min(max(i0,0),16384);
        float rg = (float)i0 * (1.0f/16384.0f);
        float tt = (rg - fmu)*fsi;
        float Lc = logf(fsg) + LSQ;
        float sc = expf(-Lc) / (expf(-0.5f*tt*tt - Lc) + 1e-8f);
        float tmu = P[2];
        float tsg = 1e-8f + P[3]*0.1f;
        float tsi = 1.0f/tsg;
        int i1 = (int)floorf(tmu*32767.0f + 0.5f);
        i1 = min(max(i1,0),32767);
        float rg1 = (float)((double)i1 * (1.0/32767.0));
        float tt1 = (rg1 - tmu)*tsi;
        float Lc1 = logf(tsg) + LSQ;
        float sc1 = expf(-Lc1) / (expf(-0.5f*tt1*tt1 - Lc1) + 1e-8f);
        float amp = P[5]*P[5];
        float* o = chP + c*8;
        o[0]=fmu; o[1]=fsi; o[2]=sc; o[3]=tmu; o[4]=tsi; o[5]=sc1; o[6]=amp; o[7]=0.f;
    }
    if (q < 4) {
        int b = q;
        mxA[b] = 1.0f/(1.0f + expf(-MXR[b]));
        const float* rl = RL + b*8;
        float mx = rl[0];
        for (int r=1;r<8;r++) mx = fmaxf(mx, rl[r]);
        float sum=0.f;
        float e2[8];
        for (int r=0;r<8;r++){ e2[r]=expf(rl[r]-mx); sum+=e2[r]; }
        for (int r=0;r<8;r++) rmA[b*8+r] = e2[r]/sum;
    }
}

// ---------------- resonances: Q32 wraparound phase + hardware v_sin ----------------
// Includes delta-impulse (+1 at t=0) so conv(loc, res+delta) = conv(loc,res)+loc.
__global__ __launch_bounds__(256) void mfk_reson(const unsigned* __restrict__ chQ,
        const float* __restrict__ cum, float* __restrict__ reson, int g0)
{
    __shared__ float cp3[16][4];
    __shared__ unsigned qf[16];
    int j  = blockIdx.x;          // frame block 0..127
    int lc = blockIdx.y;
    int cg = g0 + lc;
    int tid = threadIdx.x;
    int base = max(j-1, 0);
    if (tid < 16) {
        int q = cg*16 + tid;
        qf[tid] = chQ[q];
        const float* crow = cum + (size_t)q*128;
        cp3[tid][0] = crow[min(base+0,127)];
        cp3[tid][1] = crow[min(base+1,127)];
        cp3[tid][2] = crow[min(base+2,127)];
    }
    __syncthreads();
    int t = j*256 + tid;
    float co = ((float)t + 0.5f)*0.00390625f - 0.5f;
    co = fminf(fmaxf(co, 0.0f), 127.0f);
    int lo = (int)floorf(co);
    float w = co - (float)lo;
    int s0 = lo - base;
    int s1 = min(lo+1, 127) - base;
    unsigned T1 = (unsigned)(t+1);
    float acc = (t == 0) ? 1.0f : 0.0f;
    #pragma unroll
    for (int hh=0; hh<16; hh++){
        float e0 = cp3[hh][s0], e1 = cp3[hh][s1];
        float env = e0 + (e1-e0)*w;
        unsigned bits = qf[hh] * T1;              // frac(fr*(t+1)) in Q32, mod 2^32 free
        float m = (float)bits * 2.3283064365386963e-10f;   // revolutions in [0,1)
        float sv;
        asm("v_sin_f32 %0, %1" : "=v"(sv) : "v"(m));       // sin(2*pi*m)
        acc = fmaf(env, sv, acc);
    }
    reson[(size_t)lc*NSAMP + t] = acc;
}

// ---------------- accumulate conv outputs into located ----------------
__global__ __launch_bounds__(256) void mfk_accum(const float2* __restrict__ U,
        float* __restrict__ located, int g0, int eStart, int eCount, int bBase)
{
    int t = blockIdx.x*256 + threadIdx.x;
    int b = bBase + blockIdx.y;
    float sum = 0.f;
    for (int ei=0; ei<eCount; ei++){
        int lc = b*32 + eStart + ei - g0;
        float2 u = U[(size_t)(lc>>1)*NPAD + t];
        sum += (lc & 1) ? u.y : u.x;
    }
    located[(size_t)b*NSAMP + t] += sum;
}

extern "C" void kernel_launch(void* const* d_in, const int* in_sizes, int n_in,
                              void* d_out, int out_size, void* d_ws, size_t ws_size,
                              hipStream_t stream)
{
    (void)in_sizes; (void)n_in; (void)out_size;
    const float* EP   = (const float*)d_in[0];
    const float* MXR  = (const float*)d_in[1];
    const float* RL   = (const float*)d_in[2];
    const float* NOISE= (const float*)d_in[3];
    const float* IR   = (const float*)d_in[4];
    float* out = (float*)d_out;
    char* w = (char*)d_ws;

    auto need = [](long long g)->long long {
        return 2LL*g*NPAD*8 + 2LL*g*NSAMP*4 + (long long)NSAMP*8
             + 1LL*NCHAIN*128*4 + (128LL*8 + NCHAIN + 4 + 32 + 4LL*NSAMP)*4 + 16384;
    };
    int G = 128;
    while (G > 4 && need(G) > (long long)ws_size) G >>= 1;

    size_t off = 0;
    auto alloc = [&](size_t bytes)->char* {
        char* p = w + off; off += (bytes + 255) & ~(size_t)255; return p;
    };
    float2*   arA    = (float2*)alloc((size_t)G*NPAD*8);
    float2*   arB    = (float2*)alloc((size_t)G*NPAD*8);
    float*    locraw = (float*) alloc((size_t)G*NSAMP*4);
    float*    reson  = (float*) alloc((size_t)G*NSAMP*4);
    float2*   nspec  = (float2*)alloc((size_t)NSAMP*8);
    float*    cum    = (float*) alloc((size_t)NCHAIN*128*4);
    float*    chP    = (float*) alloc(128*8*4);
    unsigned* chQ    = (unsigned*)alloc(NCHAIN*4);
    float*    mxA    = (float*) alloc(4*4);
    float*    rmA    = (float*) alloc(32*4);
    float*    located= (float*) alloc(4*NSAMP*4);

    (void)hipMemsetAsync(located, 0, 4*NSAMP*4, stream);
    mfk_setup<<<dim3(8),256,0,stream>>>(EP,MXR,RL,chP,chQ,cum,mxA,rmA);

    // noise forward FFT (batch 1): NOISE -> nspec
    mfk_noise_fft1<<<dim3(8),256,0,stream>>>(NOISE, arB);
    mfk_fft<16,-1><<<dim3(8,1),256,0,stream>>>(arB, arA, 16,   2048);
    mfk_fft<16,-1><<<dim3(8,1),256,0,stream>>>(arA, arB, 256,  2048);
    mfk_fft<8, -1><<<dim3(16,1),256,0,stream>>>(arB, nspec, 4096, 4096);

    for (int g0 = 0; g0 < NCH; g0 += G){
        int P = G/2;
        // inverse NSAMP (windowed noise spectrum -> locraw)
        mfk_specwin_fft1<<<dim3(8,P),256,0,stream>>>(nspec, chP, arA, g0);
        mfk_fft<16,1><<<dim3(8,P),256,0,stream>>>(arA, arB, 16,  2048);
        mfk_fft<16,1><<<dim3(8,P),256,0,stream>>>(arB, arA, 256, 2048);
        mfk_unpack_fftL<<<dim3(16,P),256,0,stream>>>(arA, chP, locraw, g0);
        // resonances (with +delta for the residual add)
        mfk_reson<<<dim3(128,G),256,0,stream>>>(chQ, cum, reson, g0);
        // forward NPAD: 2 fused double-stage kernels
        mfk_packZ_f01<<<dim3(16,G),256,0,stream>>>(locraw, reson, arA);
        mfk_f23<-1,16><<<dim3(16,G),256,0,stream>>>(arA, arB);
        // inverse NPAD: product fused, upper-half store skipped
        mfk_prod_f01<<<dim3(16,P),256,0,stream>>>(arB, arA);
        mfk_f23<1,8><<<dim3(16,P),256,0,stream>>>(arA, arB);
        int bBase, bCnt, eStart, eCount;
        if (G >= 32){ bBase = g0/32; bCnt = G/32; eStart = 0; eCount = 32; }
        else        { bBase = g0/32; bCnt = 1; eStart = g0 % 32; eCount = G; }
        mfk_accum<<<dim3(128,bCnt),256,0,stream>>>(arB, located, g0, eStart, eCount, bBase);
    }

    // wet/dry chain (batch 4 -> 2 pairs)
    mfk_dry_f01<<<dim3(16,4),256,0,stream>>>(located, rmA, IR, arA);
    mfk_f23<-1,16><<<dim3(16,4),256,0,stream>>>(arA, arB);
    mfk_prod_f01<<<dim3(16,2),256,0,stream>>>(arB, arA);
    mfk_f23_final<<<dim3(16,2),256,0,stream>>>(arA, located, mxA, out);
}

// Round 5
// 195.101 us; speedup vs baseline: 2.1170x; 1.0350x over previous
//
#include <hip/hip_runtime.h>
#include <math.h>

#define NSAMP 32768
#define NPAD  65536
#define NCH   128
#define TWO_PI 6.2831853071795864f
#define MINF ((float)(20.0/11025.0))
#define DRF  ((float)(4000.0/11025.0 - 20.0/11025.0))

__device__ __forceinline__ float2 cxmul(float2 a, float2 b){
    return make_float2(a.x*b.x - a.y*b.y, a.x*b.y + a.y*b.x);
}

template<int DIR>
__device__ __forceinline__ void fft4v(float2* v, int i0, int i1, int i2, int i3){
    float2 a=v[i0], b=v[i1], c=v[i2], d=v[i3];
    float2 t0 = make_float2(a.x+c.x, a.y+c.y);
    float2 t1 = make_float2(a.x-c.x, a.y-c.y);
    float2 t2 = make_float2(b.x+d.x, b.y+d.y);
    float2 t3 = make_float2(b.x-d.x, b.y-d.y);
    v[i0] = make_float2(t0.x+t2.x, t0.y+t2.y);
    v[i2] = make_float2(t0.x-t2.x, t0.y-t2.y);
    if (DIR < 0) {
        v[i1] = make_float2(t1.x + t3.y, t1.y - t3.x);
        v[i3] = make_float2(t1.x - t3.y, t1.y + t3.x);
    } else {
        v[i1] = make_float2(t1.x - t3.y, t1.y + t3.x);
        v[i3] = make_float2(t1.x + t3.y, t1.y - t3.x);
    }
}

template<int DIR>
__device__ __forceinline__ void twm(float2& v, float c, float s){
    float sy = (DIR<0) ? -s : s;
    v = cxmul(v, make_float2(c, sy));
}

template<int DIR>
__device__ __forceinline__ void fft16r(float2* v){
    const float C1=0.92387953251128674f, S1=0.38268343236508978f, H=0.70710678118654752f;
    fft4v<DIR>(v,0,4,8,12);
    fft4v<DIR>(v,1,5,9,13);
    fft4v<DIR>(v,2,6,10,14);
    fft4v<DIR>(v,3,7,11,15);
    twm<DIR>(v[5],  C1, S1);
    twm<DIR>(v[6],  H,  H);
    twm<DIR>(v[7],  S1, C1);
    twm<DIR>(v[9],  H,  H);
    twm<DIR>(v[10], 0.0f, 1.0f);
    twm<DIR>(v[11], -H, H);
    twm<DIR>(v[13], S1, C1);
    twm<DIR>(v[14], -H, H);
    twm<DIR>(v[15], -C1, -S1);
    fft4v<DIR>(v,0,1,2,3);
    fft4v<DIR>(v,4,5,6,7);
    fft4v<DIR>(v,8,9,10,11);
    fft4v<DIR>(v,12,13,14,15);
    // X[r] at slot ((r&3)<<2)|(r>>2)
}

template<int DIR>
__device__ __forceinline__ void fft8r(float2* v){
    const float H=0.70710678118654752f;
    #pragma unroll
    for (int n1=0;n1<4;n1++){
        float2 t=v[n1], u=v[n1+4];
        v[n1]   = make_float2(t.x+u.x, t.y+u.y);
        v[n1+4] = make_float2(t.x-u.x, t.y-u.y);
    }
    twm<DIR>(v[5], H, H);
    twm<DIR>(v[6], 0.0f, 1.0f);
    twm<DIR>(v[7], -H, H);
    fft4v<DIR>(v,0,1,2,3);
    fft4v<DIR>(v,4,5,6,7);
    // X[r] at slot ((r&1)<<2)|(r>>1)
}

__device__ __forceinline__ int slot16(int r){ return ((r&3)<<2)|(r>>2); }
__device__ __forceinline__ int slot8(int r){ return ((r&1)<<2)|(r>>1); }
__device__ __forceinline__ int lpad(int l){ return l + (l>>4); }

// twiddle powers: 1 sincos + log-depth complex-power recurrence
template<int R>
__device__ __forceinline__ void twiddle(float2* v, float ang1){
    float s,c; __sincosf(ang1,&s,&c);
    float2 w[R];
    w[1] = make_float2(c,s);
    #pragma unroll
    for (int r=2;r<R;r++) w[r] = cxmul(w[r>>1], w[r-(r>>1)]);
    #pragma unroll
    for (int r=1;r<R;r++) v[r] = cxmul(v[r], w[r]);
}

// Double-stage tail for (Ns=1, Ns=16): stage A (no twiddle) -> LDS -> stage B -> store.
// Works for NSAMP (p<8) and NPAD (p<16) with j2 = 256*p + t.
template<int DIR>
__device__ __forceinline__ void n1_tail(float2 (&v)[16], float2* lds, int t, int p,
                                        float2* __restrict__ out)
{
    fft16r<DIR>(v);
    #pragma unroll
    for (int r=0;r<16;r++) lds[lpad(256*(t>>4) + 16*(t&15) + r)] = v[slot16(r)];
    __syncthreads();
    #pragma unroll
    for (int q=0;q<16;q++) v[q] = lds[lpad(256*q + t)];
    int jm = t & 15;
    if (jm) twiddle<16>(v, (DIR<0?-TWO_PI:TWO_PI)*(float)jm*(1.0f/256.0f));
    fft16r<DIR>(v);
    int j2 = 256*p + t;
    float2* yo = out + (j2>>4)*256 + (j2&15);
    #pragma unroll
    for (int r=0;r<16;r++) yo[16*r] = v[slot16(r)];
}

// ---------------- NSAMP fused kernels ----------------
// N1: stages (Ns=1, Ns=16) of 32768-FFT. thread t of block p owns stage-A j = 128*(t>>4)+16p+(t&15)
__global__ __launch_bounds__(256) void mfk_n1_noise(const float* __restrict__ noise,
                                                    float2* __restrict__ dst)
{
    __shared__ float2 lds[4352];
    int t = threadIdx.x, p = blockIdx.x;
    int j = 128*(t>>4) + 16*p + (t&15);
    float2 v[16];
    #pragma unroll
    for (int r=0;r<16;r++) v[r] = make_float2(noise[j + 2048*r], 0.0f);
    n1_tail<-1>(v, lds, t, p, dst);
}

__global__ __launch_bounds__(256) void mfk_n1_specwin(const float2* __restrict__ nspec,
        const float* __restrict__ chP, float2* __restrict__ dst, int g0)
{
    __shared__ float2 lds[4352];
    int t = threadIdx.x, p = blockIdx.x, pr = blockIdx.y;
    int c0 = g0 + 2*pr;
    const float* A = chP + c0*8;
    const float* B = chP + (c0+1)*8;
    float a0=A[0], a1=A[1], a2=A[2], b0=B[0], b1=B[1], b2=B[2];
    int j = 128*(t>>4) + 16*p + (t&15);
    float2 v[16];
    #pragma unroll
    for (int r=0;r<16;r++){
        int k = j + 2048*r;
        int kw = (k <= 16384) ? k : (32768 - k);
        float rg = (float)kw * (1.0f/16384.0f);
        float t0 = (rg - a0)*a1;
        float w0 = expf(-0.5f*t0*t0)*a2;
        float t1 = (rg - b0)*b1;
        float w1 = expf(-0.5f*t1*t1)*b2;
        float2 N = nspec[k];
        v[r] = make_float2(N.x*w0 - N.y*w1, N.y*w0 + N.x*w1);
    }
    n1_tail<1>(v, lds, t, p, dst + (size_t)pr*NSAMP);
}

// N2: stages (Ns=256 R16, Ns=4096 R8). Stage C: j2 = 256*(t>>5)+32p+(t&31).
template<int DIR>
__device__ __forceinline__ void n2_stageC(const float2* __restrict__ x, float2* lds, int t, int p)
{
    float2 v[16];
    int j2 = 256*(t>>5) + 32*p + (t&31);
    #pragma unroll
    for (int r=0;r<16;r++) v[r] = x[j2 + 2048*r];
    int jm = 32*p + (t&31);
    if (jm) twiddle<16>(v, (DIR<0?-TWO_PI:TWO_PI)*(float)jm*(1.0f/4096.0f));
    fft16r<DIR>(v);
    #pragma unroll
    for (int r=0;r<16;r++) lds[lpad(256*r + t)] = v[slot16(r)];
    __syncthreads();
}

template<int DIR>
__device__ __forceinline__ int n2_stageD(float2* lds, int t, int p, int u, float2 (&w8)[8])
{
    int q = t + 256*u;
    int j3 = ((q>>5)<<8) + 32*p + (q&31);
    #pragma unroll
    for (int r3=0;r3<8;r3++) w8[r3] = lds[lpad(256*(q>>5) + 32*r3 + (q&31))];
    if (j3) twiddle<8>(w8, (DIR<0?-TWO_PI:TWO_PI)*(float)j3*(1.0f/32768.0f));
    fft8r<DIR>(w8);
    return j3;
}

__global__ __launch_bounds__(256) void mfk_n2_noise(const float2* __restrict__ src,
                                                    float2* __restrict__ dst)
{
    __shared__ float2 lds[4352];
    int t = threadIdx.x, p = blockIdx.x;
    n2_stageC<-1>(src, lds, t, p);
    #pragma unroll
    for (int u=0;u<2;u++){
        float2 w8[8];
        int j3 = n2_stageD<-1>(lds, t, p, u, w8);
        #pragma unroll
        for (int r=0;r<8;r++) dst[j3 + 4096*r] = w8[slot8(r)];
    }
}

__global__ __launch_bounds__(256) void mfk_n2_unpack(const float2* __restrict__ src,
        const float* __restrict__ chP, float* __restrict__ locraw, int g0)
{
    __shared__ float2 lds[4352];
    int t = threadIdx.x, p = blockIdx.x, pr = blockIdx.y;
    n2_stageC<1>(src + (size_t)pr*NSAMP, lds, t, p);
    int lc0 = 2*pr;
    const float* C0 = chP + (g0+lc0)*8;
    const float* C1 = chP + (g0+lc0+1)*8;
    float c03=C0[3], c04=C0[4], c05=C0[5], c06=C0[6];
    float c13=C1[3], c14=C1[4], c15=C1[5], c16=C1[6];
    #pragma unroll
    for (int u=0;u<2;u++){
        float2 w8[8];
        int j3 = n2_stageD<1>(lds, t, p, u, w8);
        #pragma unroll
        for (int r=0;r<8;r++){
            int n = j3 + 4096*r;
            float2 val = w8[slot8(r)];
            float rg = (float)((double)n * (1.0/32767.0));
            float tt0 = (rg - c03)*c04;
            float ew0 = expf(-0.5f*tt0*tt0)*c05;
            float tt1 = (rg - c13)*c14;
            float ew1 = expf(-0.5f*tt1*tt1)*c15;
            locraw[(size_t)lc0*NSAMP + n]     = val.x*(1.0f/32768.0f)*ew0*c06;
            locraw[(size_t)(lc0+1)*NSAMP + n] = val.y*(1.0f/32768.0f)*ew1*c16;
        }
    }
}

// ---------------- NPAD kernels ----------------
// packZ + in-register resonance synthesis + stages (Ns=1,16) of 65536-FFT.
__global__ __launch_bounds__(256) void mfk_packZres_f01(const float* __restrict__ locraw,
        const float* __restrict__ EP, float2* __restrict__ dst, int g0)
{
    __shared__ float2 lds[4352];
    __shared__ float cumS[16][128];
    __shared__ unsigned qS[16];
    int t = threadIdx.x, p = blockIdx.x, lc = blockIdx.y;
    int cg = g0 + lc;
    if (t < 16){
        const float* P = EP + cg*22;
        float f0m = __fmul_rn(P[4],P[4]);
        float f0s = __fadd_rn(MINF, __fmul_rn(f0m, DRF));
        float fr  = __fmul_rn(f0s, (float)(t+1));
        if (fr >= 1.0f) fr = 0.0f;
        qS[t] = (unsigned)(unsigned long long)((double)fr*4294967296.0 + 0.5);
        float rs = __fadd_rn(__fmul_rn(P[6+t],0.2f),0.8f);
        float cp = rs;
        for (int jj=0;jj<128;jj++){ cumS[t][jj] = cp; cp = __fmul_rn(cp, rs); }
    }
    __syncthreads();
    int j = 256*(t>>4) + 16*p + (t&15);
    const float* la = locraw + (size_t)lc*NSAMP;
    float2 v[16];
    #pragma unroll
    for (int r=0;r<8;r++){
        int n = j + 4096*r;
        float co = ((float)n + 0.5f)*0.00390625f - 0.5f;
        co = fminf(fmaxf(co,0.0f),127.0f);
        int lo = (int)co;
        float wf = co - (float)lo;
        int hi = min(lo+1,127);
        unsigned T1 = (unsigned)(n+1);
        float acc = (n==0) ? 1.0f : 0.0f;   // +delta carries the residual "+located" through conv
        #pragma unroll
        for (int hh=0; hh<16; hh++){
            float e0 = cumS[hh][lo], e1 = cumS[hh][hi];
            float env = e0 + (e1-e0)*wf;
            unsigned bits = qS[hh]*T1;      // frac(fr*(n+1)) in Q32 (mod 2^32 free)
            float m = (float)bits * 2.3283064365386963e-10f;
            float sv; asm("v_sin_f32 %0, %1" : "=v"(sv) : "v"(m));
            acc = fmaf(env, sv, acc);
        }
        v[r] = make_float2(la[n], acc);
    }
    #pragma unroll
    for (int r=8;r<16;r++) v[r] = make_float2(0.f,0.f);
    n1_tail<-1>(v, lds, t, p, dst + (size_t)lc*NPAD);
}

// Hermitian-pair product + stages (Ns=1,16). blockIdx.x remapped so mirror-mate
// blocks (p, 15-p) land on the same XCD (x and x+8).
__global__ __launch_bounds__(256) void mfk_prod_f01(const float2* __restrict__ Z,
        float2* __restrict__ dst)
{
    __shared__ float2 lds[4352];
    int t = threadIdx.x;
    int px = blockIdx.x;
    int p = (px < 8) ? px : 23 - px;
    int pr = blockIdx.y;
    const float2* z0 = Z + (size_t)(2*pr)*NPAD;
    const float2* z1 = z0 + NPAD;
    int j = 256*(t>>4) + 16*p + (t&15);
    float2 v[16];
    #pragma unroll
    for (int r=0;r<16;r++){
        int k = j + 4096*r;
        int km = (NPAD - k) & (NPAD-1);
        float2 a = z0[k], am = z0[km];
        float2 A0 = make_float2(0.5f*(a.x+am.x), 0.5f*(a.y-am.y));
        float2 R0 = make_float2(0.5f*(a.y+am.y), -0.5f*(a.x-am.x));
        float2 P0 = cxmul(A0,R0);
        float2 b = z1[k], bm = z1[km];
        float2 A1 = make_float2(0.5f*(b.x+bm.x), 0.5f*(b.y-bm.y));
        float2 R1 = make_float2(0.5f*(b.y+bm.y), -0.5f*(b.x-bm.x));
        float2 P1 = cxmul(A1,R1);
        const float s = 1.0f/65536.0f;
        v[r] = make_float2((P0.x - P1.y)*s, (P0.y + P1.x)*s);
    }
    n1_tail<1>(v, lds, t, p, dst + (size_t)pr*NPAD);
}

// wet chain first pair: drypack + stages (Ns=1,16)
__global__ __launch_bounds__(256) void mfk_dry_f01(const float* __restrict__ located,
        const float* __restrict__ rmA, const float* __restrict__ IR, float2* __restrict__ dst)
{
    __shared__ float2 lds[4352];
    int t = threadIdx.x, p = blockIdx.x, b = blockIdx.y;
    int j = 256*(t>>4) + 16*p + (t&15);
    float rm[8];
    #pragma unroll
    for (int r=0;r<8;r++) rm[r] = rmA[b*8+r];
    float2 v[16];
    #pragma unroll
    for (int r=0;r<8;r++){
        int n = j + 4096*r;
        float iv = 0.f;
        #pragma unroll
        for (int q=0;q<8;q++) iv += rm[q]*IR[(size_t)q*NSAMP + n];
        v[r] = make_float2(located[(size_t)b*NSAMP + n], iv);
    }
    #pragma unroll
    for (int r=8;r<16;r++) v[r] = make_float2(0.f,0.f);
    n1_tail<-1>(v, lds, t, p, dst + (size_t)b*NPAD);
}

// stages (Ns=256, 4096) of 65536-FFT; NSTORE=8 skips discarded upper half.
template<int DIR, int NSTORE>
__global__ __launch_bounds__(256) void mfk_f23(const float2* __restrict__ src,
                                               float2* __restrict__ dst)
{
    __shared__ float2 lds[4352];
    int t = threadIdx.x, p = blockIdx.x;
    size_t boff = (size_t)blockIdx.y * NPAD;
    int a = t>>4, w = t&15;
    int j = 256*a + 16*p + w;
    const float2* x = src + boff;
    float2 v[16];
    #pragma unroll
    for (int r=0;r<16;r++) v[r] = x[j + 4096*r];
    int jm = 16*p + w;
    if (jm) twiddle<16>(v, (DIR<0?-TWO_PI:TWO_PI)*(float)jm*(1.0f/4096.0f));
    fft16r<DIR>(v);
    #pragma unroll
    for (int r=0;r<16;r++) lds[lpad(256*a + 16*r + w)] = v[slot16(r)];
    __syncthreads();
    #pragma unroll
    for (int q=0;q<16;q++) v[q] = lds[lpad(256*q + t)];
    if (j) twiddle<16>(v, (DIR<0?-TWO_PI:TWO_PI)*(float)j*(1.0f/65536.0f));
    fft16r<DIR>(v);
    float2* yo = dst + boff + j;
    #pragma unroll
    for (int r=0;r<NSTORE;r++) yo[4096*r] = v[slot16(r)];
}

// wet chain last pair: stages (256,4096) + final mix, writes out
__global__ __launch_bounds__(256) void mfk_f23_final(const float2* __restrict__ src,
        const float* __restrict__ located, const float* __restrict__ mxA,
        float* __restrict__ out)
{
    __shared__ float2 lds[4352];
    int t = threadIdx.x, p = blockIdx.x;
    size_t boff = (size_t)blockIdx.y * NPAD;
    int a = t>>4, w = t&15;
    int j = 256*a + 16*p + w;
    const float2* x = src + boff;
    float2 v[16];
    #pragma unroll
    for (int r=0;r<16;r++) v[r] = x[j + 4096*r];
    int jm = 16*p + w;
    if (jm) twiddle<16>(v, TWO_PI*(float)jm*(1.0f/4096.0f));
    fft16r<1>(v);
    #pragma unroll
    for (int r=0;r<16;r++) lds[lpad(256*a + 16*r + w)] = v[slot16(r)];
    __syncthreads();
    #pragma unroll
    for (int q=0;q<16;q++) v[q] = lds[lpad(256*q + t)];
    if (j) twiddle<16>(v, TWO_PI*(float)j*(1.0f/65536.0f));
    fft16r<1>(v);
    int b0 = 2*blockIdx.y, b1 = b0+1;
    float mx0 = mxA[b0], mx1 = mxA[b1];
    #pragma unroll
    for (int r=0;r<8;r++){
        int ts = j + 4096*r;
        float2 val = v[slot16(r)];
        out[(size_t)b0*NSAMP+ts] = located[(size_t)b0*NSAMP+ts]*(1.f-mx0) + val.x*mx0;
        out[(size_t)b1*NSAMP+ts] = located[(size_t)b1*NSAMP+ts]*(1.f-mx1) + val.y*mx1;
    }
}

// ---------------- setup (window params + mix/room weights only) ----------------
__global__ __launch_bounds__(256) void mfk_setup(const float* __restrict__ EP,
        const float* __restrict__ MXR, const float* __restrict__ RL,
        float* __restrict__ chP, float* __restrict__ mxA, float* __restrict__ rmA)
{
    int t = threadIdx.x;
    const float LSQ = (float)0.9189385332046727;
    if (t < NCH){
        const float* P = EP + t*22;
        float fm  = __fmul_rn(P[0],P[0]);
        float fmu = __fadd_rn(MINF, __fmul_rn(fm, DRF));
        float fsg = 1e-8f + P[1]*0.1f;
        float fsi = 1.0f/fsg;
        int i0 = (int)floorf(fmu*16384.0f + 0.5f);
        i0 = min(max(i0,0),16384);
        float rg = (float)i0 * (1.0f/16384.0f);
        float tt = (rg - fmu)*fsi;
        float Lc = logf(fsg) + LSQ;
        float sc = expf(-Lc) / (expf(-0.5f*tt*tt - Lc) + 1e-8f);
        float tmu = P[2];
        float tsg = 1e-8f + P[3]*0.1f;
        float tsi = 1.0f/tsg;
        int i1 = (int)floorf(tmu*32767.0f + 0.5f);
        i1 = min(max(i1,0),32767);
        float rg1 = (float)((double)i1 * (1.0/32767.0));
        float tt1 = (rg1 - tmu)*tsi;
        float Lc1 = logf(tsg) + LSQ;
        float sc1 = expf(-Lc1) / (expf(-0.5f*tt1*tt1 - Lc1) + 1e-8f);
        float amp = P[5]*P[5];
        float* o = chP + t*8;
        o[0]=fmu; o[1]=fsi; o[2]=sc; o[3]=tmu; o[4]=tsi; o[5]=sc1; o[6]=amp; o[7]=0.f;
    }
    if (t < 4){
        int b = t;
        mxA[b] = 1.0f/(1.0f + expf(-MXR[b]));
        const float* rl = RL + b*8;
        float mx = rl[0];
        for (int r=1;r<8;r++) mx = fmaxf(mx, rl[r]);
        float sum=0.f;
        float e2[8];
        for (int r=0;r<8;r++){ e2[r]=expf(rl[r]-mx); sum+=e2[r]; }
        for (int r=0;r<8;r++) rmA[b*8+r] = e2[r]/sum;
    }
}

// ---------------- accumulate conv outputs into located ----------------
__global__ __launch_bounds__(256) void mfk_accum(const float2* __restrict__ U,
        float* __restrict__ located, int g0, int eStart, int eCount, int bBase, int addTo)
{
    int t = blockIdx.x*256 + threadIdx.x;
    int b = bBase + blockIdx.y;
    float sum = 0.f;
    for (int ei=0; ei<eCount; ei++){
        int lc = b*32 + eStart + ei - g0;
        float2 u = U[(size_t)(lc>>1)*NPAD + t];
        sum += (lc & 1) ? u.y : u.x;
    }
    size_t idx = (size_t)b*NSAMP + t;
    float base0 = addTo ? located[idx] : 0.0f;
    located[idx] = base0 + sum;
}

extern "C" void kernel_launch(void* const* d_in, const int* in_sizes, int n_in,
                              void* d_out, int out_size, void* d_ws, size_t ws_size,
                              hipStream_t stream)
{
    (void)in_sizes; (void)n_in; (void)out_size;
    const float* EP   = (const float*)d_in[0];
    const float* MXR  = (const float*)d_in[1];
    const float* RL   = (const float*)d_in[2];
    const float* NOISE= (const float*)d_in[3];
    const float* IR   = (const float*)d_in[4];
    float* out = (float*)d_out;
    char* w = (char*)d_ws;

    auto need = [](long long g)->long long {
        return 2LL*g*NPAD*8 + 1LL*g*NSAMP*4 + (long long)NSAMP*8
             + (128LL*8 + 4 + 32 + 4LL*NSAMP)*4 + 16384;
    };
    int G = 128;
    while (G > 4 && need(G) > (long long)ws_size) G >>= 1;

    size_t off = 0;
    auto alloc = [&](size_t bytes)->char* {
        char* p = w + off; off += (bytes + 255) & ~(size_t)255; return p;
    };
    float2*   arA    = (float2*)alloc((size_t)G*NPAD*8);
    float2*   arB    = (float2*)alloc((size_t)G*NPAD*8);
    float*    locraw = (float*) alloc((size_t)G*NSAMP*4);
    float2*   nspec  = (float2*)alloc((size_t)NSAMP*8);
    float*    chP    = (float*) alloc(128*8*4);
    float*    mxA    = (float*) alloc(4*4);
    float*    rmA    = (float*) alloc(32*4);
    float*    located= (float*) alloc(4*NSAMP*4);

    mfk_setup<<<dim3(1),256,0,stream>>>(EP,MXR,RL,chP,mxA,rmA);

    // noise forward FFT (batch 1): NOISE -> nspec  (2 fused kernels)
    mfk_n1_noise<<<dim3(8),256,0,stream>>>(NOISE, arB);
    mfk_n2_noise<<<dim3(8),256,0,stream>>>(arB, nspec);

    for (int g0 = 0; g0 < NCH; g0 += G){
        int P = G/2;
        // inverse NSAMP (windowed noise spectrum -> locraw), 2 fused kernels
        mfk_n1_specwin<<<dim3(8,P),256,0,stream>>>(nspec, chP, arA, g0);
        mfk_n2_unpack<<<dim3(8,P),256,0,stream>>>(arA, chP, locraw, g0);
        // forward NPAD (located + i*reson synthesized in-register)
        mfk_packZres_f01<<<dim3(16,G),256,0,stream>>>(locraw, EP, arA, g0);
        mfk_f23<-1,16><<<dim3(16,G),256,0,stream>>>(arA, arB);
        // inverse NPAD: Hermitian product fused, upper-half store skipped
        mfk_prod_f01<<<dim3(16,P),256,0,stream>>>(arB, arA);
        mfk_f23<1,8><<<dim3(16,P),256,0,stream>>>(arA, arB);
        int bBase, bCnt, eStart, eCount;
        if (G >= 32){ bBase = g0/32; bCnt = G/32; eStart = 0; eCount = 32; }
        else        { bBase = g0/32; bCnt = 1; eStart = g0 % 32; eCount = G; }
        int addTo = (eStart != 0);
        mfk_accum<<<dim3(128,bCnt),256,0,stream>>>(arB, located, g0, eStart, eCount, bBase, addTo);
    }

    // wet/dry chain (batch 4 -> 2 pairs)
    mfk_dry_f01<<<dim3(16,4),256,0,stream>>>(located, rmA, IR, arA);
    mfk_f23<-1,16><<<dim3(16,4),256,0,stream>>>(arA, arB);
    mfk_prod_f01<<<dim3(16,2),256,0,stream>>>(arB, arA);
    mfk_f23_final<<<dim3(16,2),256,0,stream>>>(arA, located, mxA, out);
}

// Round 6
// 185.512 us; speedup vs baseline: 2.2264x; 1.0517x over previous
//
#include <hip/hip_runtime.h>
#include <math.h>

#define NSAMP 32768
#define NPAD  65536
#define NCH   128
#define TWO_PI 6.2831853071795864f
#define MINF ((float)(20.0/11025.0))
#define DRF  ((float)(4000.0/11025.0 - 20.0/11025.0))

__device__ __forceinline__ float2 cxmul(float2 a, float2 b){
    return make_float2(a.x*b.x - a.y*b.y, a.x*b.y + a.y*b.x);
}

template<int DIR>
__device__ __forceinline__ void fft4v(float2* v, int i0, int i1, int i2, int i3){
    float2 a=v[i0], b=v[i1], c=v[i2], d=v[i3];
    float2 t0 = make_float2(a.x+c.x, a.y+c.y);
    float2 t1 = make_float2(a.x-c.x, a.y-c.y);
    float2 t2 = make_float2(b.x+d.x, b.y+d.y);
    float2 t3 = make_float2(b.x-d.x, b.y-d.y);
    v[i0] = make_float2(t0.x+t2.x, t0.y+t2.y);
    v[i2] = make_float2(t0.x-t2.x, t0.y-t2.y);
    if (DIR < 0) {
        v[i1] = make_float2(t1.x + t3.y, t1.y - t3.x);
        v[i3] = make_float2(t1.x - t3.y, t1.y + t3.x);
    } else {
        v[i1] = make_float2(t1.x - t3.y, t1.y + t3.x);
        v[i3] = make_float2(t1.x + t3.y, t1.y - t3.x);
    }
}

template<int DIR>
__device__ __forceinline__ void twm(float2& v, float c, float s){
    float sy = (DIR<0) ? -s : s;
    v = cxmul(v, make_float2(c, sy));
}

template<int DIR>
__device__ __forceinline__ void fft16r(float2* v){
    const float C1=0.92387953251128674f, S1=0.38268343236508978f, H=0.70710678118654752f;
    fft4v<DIR>(v,0,4,8,12);
    fft4v<DIR>(v,1,5,9,13);
    fft4v<DIR>(v,2,6,10,14);
    fft4v<DIR>(v,3,7,11,15);
    twm<DIR>(v[5],  C1, S1);
    twm<DIR>(v[6],  H,  H);
    twm<DIR>(v[7],  S1, C1);
    twm<DIR>(v[9],  H,  H);
    twm<DIR>(v[10], 0.0f, 1.0f);
    twm<DIR>(v[11], -H, H);
    twm<DIR>(v[13], S1, C1);
    twm<DIR>(v[14], -H, H);
    twm<DIR>(v[15], -C1, -S1);
    fft4v<DIR>(v,0,1,2,3);
    fft4v<DIR>(v,4,5,6,7);
    fft4v<DIR>(v,8,9,10,11);
    fft4v<DIR>(v,12,13,14,15);
    // X[r] at slot ((r&3)<<2)|(r>>2)
}

template<int DIR>
__device__ __forceinline__ void fft8r(float2* v){
    const float H=0.70710678118654752f;
    #pragma unroll
    for (int n1=0;n1<4;n1++){
        float2 t=v[n1], u=v[n1+4];
        v[n1]   = make_float2(t.x+u.x, t.y+u.y);
        v[n1+4] = make_float2(t.x-u.x, t.y-u.y);
    }
    twm<DIR>(v[5], H, H);
    twm<DIR>(v[6], 0.0f, 1.0f);
    twm<DIR>(v[7], -H, H);
    fft4v<DIR>(v,0,1,2,3);
    fft4v<DIR>(v,4,5,6,7);
    // X[r] at slot ((r&1)<<2)|(r>>1)
}

__device__ __forceinline__ int slot16(int r){ return ((r&3)<<2)|(r>>2); }
__device__ __forceinline__ int slot8(int r){ return ((r&1)<<2)|(r>>1); }
__device__ __forceinline__ int lpad(int l){ return l + (l>>4); }

// twiddle powers: 1 sincos + log-depth complex-power recurrence
template<int R>
__device__ __forceinline__ void twiddle(float2* v, float ang1){
    float s,c; __sincosf(ang1,&s,&c);
    float2 w[R];
    w[1] = make_float2(c,s);
    #pragma unroll
    for (int r=2;r<R;r++) w[r] = cxmul(w[r>>1], w[r-(r>>1)]);
    #pragma unroll
    for (int r=1;r<R;r++) v[r] = cxmul(v[r], w[r]);
}

// Double-stage tail for (Ns=1, Ns=16): stage A (no twiddle) -> LDS -> stage B -> store.
template<int DIR>
__device__ __forceinline__ void n1_tail(float2 (&v)[16], float2* lds, int t, int p,
                                        float2* __restrict__ out)
{
    fft16r<DIR>(v);
    #pragma unroll
    for (int r=0;r<16;r++) lds[lpad(256*(t>>4) + 16*(t&15) + r)] = v[slot16(r)];
    __syncthreads();
    #pragma unroll
    for (int q=0;q<16;q++) v[q] = lds[lpad(256*q + t)];
    int jm = t & 15;
    if (jm) twiddle<16>(v, (DIR<0?-TWO_PI:TWO_PI)*(float)jm*(1.0f/256.0f));
    fft16r<DIR>(v);
    int j2 = 256*p + t;
    float2* yo = out + (j2>>4)*256 + (j2&15);
    #pragma unroll
    for (int r=0;r<16;r++) yo[16*r] = v[slot16(r)];
}

// ---------------- N1 noise + full parameter setup (blocks 8..15) ----------------
__global__ __launch_bounds__(256) void mfk_n1_noise_setup(const float* __restrict__ noise,
        float2* __restrict__ dst, const float* __restrict__ EP,
        const float* __restrict__ MXR, const float* __restrict__ RL,
        float* __restrict__ chP, unsigned* __restrict__ chQ, float* __restrict__ cum,
        float* __restrict__ mxA, float* __restrict__ rmA)
{
    __shared__ float2 lds[4352];
    int t = threadIdx.x, px = blockIdx.x;
    if (px >= 8){
        int q = (px-8)*256 + t;          // chain id 0..2047
        int c = q >> 4, h = q & 15;
        const float* P = EP + c*22;
        const float LSQ = (float)0.9189385332046727;
        float f0m = __fmul_rn(P[4],P[4]);
        float f0s = __fadd_rn(MINF, __fmul_rn(f0m, DRF));
        float fr  = __fmul_rn(f0s, (float)(h+1));
        if (fr >= 1.0f) fr = 0.0f;
        chQ[q] = (unsigned)(unsigned long long)((double)fr*4294967296.0 + 0.5);
        float rs = __fadd_rn(__fmul_rn(P[6+h],0.2f),0.8f);
        float cp = rs;
        float* crow = cum + (size_t)q*128;
        for (int jj=0;jj<128;jj++){ crow[jj] = cp; cp = __fmul_rn(cp, rs); }
        if (h == 0){
            float fm  = __fmul_rn(P[0],P[0]);
            float fmu = __fadd_rn(MINF, __fmul_rn(fm, DRF));
            float fsg = 1e-8f + P[1]*0.1f;
            float fsi = 1.0f/fsg;
            int i0 = (int)floorf(fmu*16384.0f + 0.5f);
            i0 = min(max(i0,0),16384);
            float rg = (float)i0 * (1.0f/16384.0f);
            float tt = (rg - fmu)*fsi;
            float Lc = logf(fsg) + LSQ;
            float sc = expf(-Lc) / (expf(-0.5f*tt*tt - Lc) + 1e-8f);
            float tmu = P[2];
            float tsg = 1e-8f + P[3]*0.1f;
            float tsi = 1.0f/tsg;
            int i1 = (int)floorf(tmu*32767.0f + 0.5f);
            i1 = min(max(i1,0),32767);
            float rg1 = (float)((double)i1 * (1.0/32767.0));
            float tt1 = (rg1 - tmu)*tsi;
            float Lc1 = logf(tsg) + LSQ;
            float sc1 = expf(-Lc1) / (expf(-0.5f*tt1*tt1 - Lc1) + 1e-8f);
            float amp = P[5]*P[5];
            float* o = chP + c*8;
            o[0]=fmu; o[1]=fsi; o[2]=sc; o[3]=tmu; o[4]=tsi; o[5]=sc1; o[6]=amp; o[7]=0.f;
        }
        if (q < 4){
            int b = q;
            mxA[b] = 1.0f/(1.0f + expf(-MXR[b]));
            const float* rl = RL + b*8;
            float mx = rl[0];
            for (int r=1;r<8;r++) mx = fmaxf(mx, rl[r]);
            float sum=0.f;
            float e2[8];
            for (int r=0;r<8;r++){ e2[r]=expf(rl[r]-mx); sum+=e2[r]; }
            for (int r=0;r<8;r++) rmA[b*8+r] = e2[r]/sum;
        }
        return;
    }
    int p = px;
    int j = 128*(t>>4) + 16*p + (t&15);
    float2 v[16];
    #pragma unroll
    for (int r=0;r<16;r++) v[r] = make_float2(noise[j + 2048*r], 0.0f);
    n1_tail<-1>(v, lds, t, p, dst);
}

__global__ __launch_bounds__(256) void mfk_n1_specwin(const float2* __restrict__ nspec,
        const float* __restrict__ chP, float2* __restrict__ dst, int g0)
{
    __shared__ float2 lds[4352];
    int t = threadIdx.x, p = blockIdx.x, pr = blockIdx.y;
    int c0 = g0 + 2*pr;
    const float* A = chP + c0*8;
    const float* B = chP + (c0+1)*8;
    float a0=A[0], a1=A[1], a2=A[2], b0=B[0], b1=B[1], b2=B[2];
    int j = 128*(t>>4) + 16*p + (t&15);
    float2 v[16];
    #pragma unroll
    for (int r=0;r<16;r++){
        int k = j + 2048*r;
        int kw = (k <= 16384) ? k : (32768 - k);
        float rg = (float)kw * (1.0f/16384.0f);
        float t0 = (rg - a0)*a1;
        float w0 = expf(-0.5f*t0*t0)*a2;
        float t1 = (rg - b0)*b1;
        float w1 = expf(-0.5f*t1*t1)*b2;
        float2 N = nspec[k];
        v[r] = make_float2(N.x*w0 - N.y*w1, N.y*w0 + N.x*w1);
    }
    n1_tail<1>(v, lds, t, p, dst + (size_t)pr*NSAMP);
}

// N2: stages (Ns=256 R16, Ns=4096 R8). Stage C: j2 = 256*(t>>5)+32p+(t&31).
template<int DIR>
__device__ __forceinline__ void n2_stageC(const float2* __restrict__ x, float2* lds, int t, int p)
{
    float2 v[16];
    int j2 = 256*(t>>5) + 32*p + (t&31);
    #pragma unroll
    for (int r=0;r<16;r++) v[r] = x[j2 + 2048*r];
    int jm = 32*p + (t&31);
    if (jm) twiddle<16>(v, (DIR<0?-TWO_PI:TWO_PI)*(float)jm*(1.0f/4096.0f));
    fft16r<DIR>(v);
    #pragma unroll
    for (int r=0;r<16;r++) lds[lpad(256*r + t)] = v[slot16(r)];
    __syncthreads();
}

template<int DIR>
__device__ __forceinline__ int n2_stageD(float2* lds, int t, int p, int u, float2 (&w8)[8])
{
    int q = t + 256*u;
    int j3 = ((q>>5)<<8) + 32*p + (q&31);
    #pragma unroll
    for (int r3=0;r3<8;r3++) w8[r3] = lds[lpad(256*(q>>5) + 32*r3 + (q&31))];
    if (j3) twiddle<8>(w8, (DIR<0?-TWO_PI:TWO_PI)*(float)j3*(1.0f/32768.0f));
    fft8r<DIR>(w8);
    return j3;
}

__global__ __launch_bounds__(256) void mfk_n2_noise(const float2* __restrict__ src,
                                                    float2* __restrict__ dst)
{
    __shared__ float2 lds[4352];
    int t = threadIdx.x, p = blockIdx.x;
    n2_stageC<-1>(src, lds, t, p);
    #pragma unroll
    for (int u=0;u<2;u++){
        float2 w8[8];
        int j3 = n2_stageD<-1>(lds, t, p, u, w8);
        #pragma unroll
        for (int r=0;r<8;r++) dst[j3 + 4096*r] = w8[slot8(r)];
    }
}

__global__ __launch_bounds__(256) void mfk_n2_unpack(const float2* __restrict__ src,
        const float* __restrict__ chP, float* __restrict__ locraw, int g0)
{
    __shared__ float2 lds[4352];
    int t = threadIdx.x, p = blockIdx.x, pr = blockIdx.y;
    n2_stageC<1>(src + (size_t)pr*NSAMP, lds, t, p);
    int lc0 = 2*pr;
    const float* C0 = chP + (g0+lc0)*8;
    const float* C1 = chP + (g0+lc0+1)*8;
    float c03=C0[3], c04=C0[4], c05=C0[5], c06=C0[6];
    float c13=C1[3], c14=C1[4], c15=C1[5], c16=C1[6];
    #pragma unroll
    for (int u=0;u<2;u++){
        float2 w8[8];
        int j3 = n2_stageD<1>(lds, t, p, u, w8);
        #pragma unroll
        for (int r=0;r<8;r++){
            int n = j3 + 4096*r;
            float2 val = w8[slot8(r)];
            float rg = (float)((double)n * (1.0/32767.0));
            float tt0 = (rg - c03)*c04;
            float ew0 = expf(-0.5f*tt0*tt0)*c05;
            float tt1 = (rg - c13)*c14;
            float ew1 = expf(-0.5f*tt1*tt1)*c15;
            locraw[(size_t)lc0*NSAMP + n]     = val.x*(1.0f/32768.0f)*ew0*c06;
            locraw[(size_t)(lc0+1)*NSAMP + n] = val.y*(1.0f/32768.0f)*ew1*c16;
        }
    }
}

// ---------------- NPAD kernels ----------------
// packZ + in-register resonance synthesis + stages (Ns=1,16) of 65536-FFT.
// cum rows are loaded coalesced into LDS (union'd with the FFT buffer).
__global__ __launch_bounds__(256) void mfk_packZres_f01(const float* __restrict__ locraw,
        const unsigned* __restrict__ chQ, const float* __restrict__ cum,
        float2* __restrict__ dst, int g0)
{
    __shared__ float2 lds[4352];
    __shared__ unsigned qS[16];
    float* cumS = (float*)lds;            // first 2048 floats, dead before n1_tail
    int t = threadIdx.x, p = blockIdx.x, lc = blockIdx.y;
    int cg = g0 + lc;
    const float* crow = cum + (size_t)cg*2048;
    #pragma unroll
    for (int i=0;i<8;i++) cumS[t + 256*i] = crow[t + 256*i];
    if (t < 16) qS[t] = chQ[cg*16 + t];
    __syncthreads();
    int j = 256*(t>>4) + 16*p + (t&15);
    const float* la = locraw + (size_t)lc*NSAMP;
    float2 v[16];
    #pragma unroll
    for (int r=0;r<8;r++){
        int n = j + 4096*r;
        float co = ((float)n + 0.5f)*0.00390625f - 0.5f;
        co = fminf(fmaxf(co,0.0f),127.0f);
        int lo = (int)co;
        float wf = co - (float)lo;
        int hi = min(lo+1,127);
        unsigned T1 = (unsigned)(n+1);
        float acc = (n==0) ? 1.0f : 0.0f;   // +delta carries the residual "+located" through conv
        #pragma unroll
        for (int hh=0; hh<16; hh++){
            float e0 = cumS[hh*128+lo], e1 = cumS[hh*128+hi];
            float env = e0 + (e1-e0)*wf;
            unsigned bits = qS[hh]*T1;      // frac(fr*(n+1)) in Q32 (mod 2^32 free)
            float m = (float)bits * 2.3283064365386963e-10f;
            float sv; asm("v_sin_f32 %0, %1" : "=v"(sv) : "v"(m));
            acc = fmaf(env, sv, acc);
        }
        v[r] = make_float2(la[n], acc);
    }
    #pragma unroll
    for (int r=8;r<16;r++) v[r] = make_float2(0.f,0.f);
    __syncthreads();                       // cumS reads done before lds reuse
    n1_tail<-1>(v, lds, t, p, dst + (size_t)lc*NPAD);
}

// Hermitian-pair product + stages (Ns=1,16). blockIdx.x remapped so mirror-mate
// blocks (p, 15-p) land on the same XCD.
__global__ __launch_bounds__(256) void mfk_prod_f01(const float2* __restrict__ Z,
        float2* __restrict__ dst)
{
    __shared__ float2 lds[4352];
    int t = threadIdx.x;
    int px = blockIdx.x;
    int p = (px < 8) ? px : 23 - px;
    int pr = blockIdx.y;
    const float2* z0 = Z + (size_t)(2*pr)*NPAD;
    const float2* z1 = z0 + NPAD;
    int j = 256*(t>>4) + 16*p + (t&15);
    float2 v[16];
    #pragma unroll
    for (int r=0;r<16;r++){
        int k = j + 4096*r;
        int km = (NPAD - k) & (NPAD-1);
        float2 a = z0[k], am = z0[km];
        float2 A0 = make_float2(0.5f*(a.x+am.x), 0.5f*(a.y-am.y));
        float2 R0 = make_float2(0.5f*(a.y+am.y), -0.5f*(a.x-am.x));
        float2 P0 = cxmul(A0,R0);
        float2 b = z1[k], bm = z1[km];
        float2 A1 = make_float2(0.5f*(b.x+bm.x), 0.5f*(b.y-bm.y));
        float2 R1 = make_float2(0.5f*(b.y+bm.y), -0.5f*(b.x-bm.x));
        float2 P1 = cxmul(A1,R1);
        const float s = 1.0f/65536.0f;
        v[r] = make_float2((P0.x - P1.y)*s, (P0.y + P1.x)*s);
    }
    n1_tail<1>(v, lds, t, p, dst + (size_t)pr*NPAD);
}

// merged accum + drypack + stages (Ns=1,16): reads lower half of U, emits located
__global__ __launch_bounds__(256) void mfk_dryacc_f01(const float2* __restrict__ U,
        const float* __restrict__ rmA, const float* __restrict__ IR,
        float* __restrict__ located, float2* __restrict__ dst)
{
    __shared__ float2 lds[4352];
    int t = threadIdx.x, p = blockIdx.x, b = blockIdx.y;
    int j = 256*(t>>4) + 16*p + (t&15);
    float rm[8];
    #pragma unroll
    for (int r=0;r<8;r++) rm[r] = rmA[b*8+r];
    float2 v[16];
    #pragma unroll
    for (int r=0;r<8;r++){
        int n = j + 4096*r;
        float sum = 0.f;
        #pragma unroll
        for (int e=0;e<16;e++){
            float2 u = U[(size_t)(16*b+e)*NPAD + n];
            sum += u.x + u.y;
        }
        located[(size_t)b*NSAMP + n] = sum;
        float iv = 0.f;
        #pragma unroll
        for (int q=0;q<8;q++) iv += rm[q]*IR[(size_t)q*NSAMP + n];
        v[r] = make_float2(sum, iv);
    }
    #pragma unroll
    for (int r=8;r<16;r++) v[r] = make_float2(0.f,0.f);
    n1_tail<-1>(v, lds, t, p, dst + (size_t)b*NPAD);
}

// fallback (G<128): plain drypack
__global__ __launch_bounds__(256) void mfk_dry_f01(const float* __restrict__ located,
        const float* __restrict__ rmA, const float* __restrict__ IR, float2* __restrict__ dst)
{
    __shared__ float2 lds[4352];
    int t = threadIdx.x, p = blockIdx.x, b = blockIdx.y;
    int j = 256*(t>>4) + 16*p + (t&15);
    float rm[8];
    #pragma unroll
    for (int r=0;r<8;r++) rm[r] = rmA[b*8+r];
    float2 v[16];
    #pragma unroll
    for (int r=0;r<8;r++){
        int n = j + 4096*r;
        float iv = 0.f;
        #pragma unroll
        for (int q=0;q<8;q++) iv += rm[q]*IR[(size_t)q*NSAMP + n];
        v[r] = make_float2(located[(size_t)b*NSAMP + n], iv);
    }
    #pragma unroll
    for (int r=8;r<16;r++) v[r] = make_float2(0.f,0.f);
    n1_tail<-1>(v, lds, t, p, dst + (size_t)b*NPAD);
}

// stages (Ns=256, 4096) of 65536-FFT; NSTORE=8 skips discarded upper half.
template<int DIR, int NSTORE>
__global__ __launch_bounds__(256) void mfk_f23(const float2* __restrict__ src,
                                               float2* __restrict__ dst)
{
    __shared__ float2 lds[4352];
    int t = threadIdx.x, p = blockIdx.x;
    size_t boff = (size_t)blockIdx.y * NPAD;
    int a = t>>4, w = t&15;
    int j = 256*a + 16*p + w;
    const float2* x = src + boff;
    float2 v[16];
    #pragma unroll
    for (int r=0;r<16;r++) v[r] = x[j + 4096*r];
    int jm = 16*p + w;
    if (jm) twiddle<16>(v, (DIR<0?-TWO_PI:TWO_PI)*(float)jm*(1.0f/4096.0f));
    fft16r<DIR>(v);
    #pragma unroll
    for (int r=0;r<16;r++) lds[lpad(256*a + 16*r + w)] = v[slot16(r)];
    __syncthreads();
    #pragma unroll
    for (int q=0;q<16;q++) v[q] = lds[lpad(256*q + t)];
    if (j) twiddle<16>(v, (DIR<0?-TWO_PI:TWO_PI)*(float)j*(1.0f/65536.0f));
    fft16r<DIR>(v);
    float2* yo = dst + boff + j;
    #pragma unroll
    for (int r=0;r<NSTORE;r++) yo[4096*r] = v[slot16(r)];
}

// wet chain last pair: stages (256,4096) + final mix, writes out
__global__ __launch_bounds__(256) void mfk_f23_final(const float2* __restrict__ src,
        const float* __restrict__ located, const float* __restrict__ mxA,
        float* __restrict__ out)
{
    __shared__ float2 lds[4352];
    int t = threadIdx.x, p = blockIdx.x;
    size_t boff = (size_t)blockIdx.y * NPAD;
    int a = t>>4, w = t&15;
    int j = 256*a + 16*p + w;
    const float2* x = src + boff;
    float2 v[16];
    #pragma unroll
    for (int r=0;r<16;r++) v[r] = x[j + 4096*r];
    int jm = 16*p + w;
    if (jm) twiddle<16>(v, TWO_PI*(float)jm*(1.0f/4096.0f));
    fft16r<1>(v);
    #pragma unroll
    for (int r=0;r<16;r++) lds[lpad(256*a + 16*r + w)] = v[slot16(r)];
    __syncthreads();
    #pragma unroll
    for (int q=0;q<16;q++) v[q] = lds[lpad(256*q + t)];
    if (j) twiddle<16>(v, TWO_PI*(float)j*(1.0f/65536.0f));
    fft16r<1>(v);
    int b0 = 2*blockIdx.y, b1 = b0+1;
    float mx0 = mxA[b0], mx1 = mxA[b1];
    #pragma unroll
    for (int r=0;r<8;r++){
        int ts = j + 4096*r;
        float2 val = v[slot16(r)];
        out[(size_t)b0*NSAMP+ts] = located[(size_t)b0*NSAMP+ts]*(1.f-mx0) + val.x*mx0;
        out[(size_t)b1*NSAMP+ts] = located[(size_t)b1*NSAMP+ts]*(1.f-mx1) + val.y*mx1;
    }
}

// ---------------- accumulate conv outputs into located (G<128 fallback) ----------------
__global__ __launch_bounds__(256) void mfk_accum(const float2* __restrict__ U,
        float* __restrict__ located, int g0, int eStart, int eCount, int bBase, int addTo)
{
    int t = blockIdx.x*256 + threadIdx.x;
    int b = bBase + blockIdx.y;
    float sum = 0.f;
    for (int ei=0; ei<eCount; ei++){
        int lc = b*32 + eStart + ei - g0;
        float2 u = U[(size_t)(lc>>1)*NPAD + t];
        sum += (lc & 1) ? u.y : u.x;
    }
    size_t idx = (size_t)b*NSAMP + t;
    float base0 = addTo ? located[idx] : 0.0f;
    located[idx] = base0 + sum;
}

extern "C" void kernel_launch(void* const* d_in, const int* in_sizes, int n_in,
                              void* d_out, int out_size, void* d_ws, size_t ws_size,
                              hipStream_t stream)
{
    (void)in_sizes; (void)n_in; (void)out_size;
    const float* EP   = (const float*)d_in[0];
    const float* MXR  = (const float*)d_in[1];
    const float* RL   = (const float*)d_in[2];
    const float* NOISE= (const float*)d_in[3];
    const float* IR   = (const float*)d_in[4];
    float* out = (float*)d_out;
    char* w = (char*)d_ws;

    auto need = [](long long g)->long long {
        return 2LL*g*NPAD*8 + 1LL*g*NSAMP*4 + (long long)NSAMP*8
             + 2048LL*128*4 + (128LL*8 + 2048 + 4 + 32 + 4LL*NSAMP)*4 + 16384;
    };
    int G = 128;
    while (G > 4 && need(G) > (long long)ws_size) G >>= 1;

    size_t off = 0;
    auto alloc = [&](size_t bytes)->char* {
        char* p = w + off; off += (bytes + 255) & ~(size_t)255; return p;
    };
    float2*   arA    = (float2*)alloc((size_t)G*NPAD*8);
    float2*   arB    = (float2*)alloc((size_t)G*NPAD*8);
    float*    locraw = (float*) alloc((size_t)G*NSAMP*4);
    float2*   nspec  = (float2*)alloc((size_t)NSAMP*8);
    float*    cum    = (float*) alloc(2048LL*128*4);
    float*    chP    = (float*) alloc(128*8*4);
    unsigned* chQ    = (unsigned*)alloc(2048*4);
    float*    mxA    = (float*) alloc(4*4);
    float*    rmA    = (float*) alloc(32*4);
    float*    located= (float*) alloc(4*NSAMP*4);

    // noise N1 (blocks 0..7) + full setup (blocks 8..15)
    mfk_n1_noise_setup<<<dim3(16),256,0,stream>>>(NOISE, arB, EP, MXR, RL,
                                                  chP, chQ, cum, mxA, rmA);
    mfk_n2_noise<<<dim3(8),256,0,stream>>>(arB, nspec);

    for (int g0 = 0; g0 < NCH; g0 += G){
        int P = G/2;
        mfk_n1_specwin<<<dim3(8,P),256,0,stream>>>(nspec, chP, arA, g0);
        mfk_n2_unpack<<<dim3(8,P),256,0,stream>>>(arA, chP, locraw, g0);
        mfk_packZres_f01<<<dim3(16,G),256,0,stream>>>(locraw, chQ, cum, arA, g0);
        mfk_f23<-1,16><<<dim3(16,G),256,0,stream>>>(arA, arB);
        mfk_prod_f01<<<dim3(16,P),256,0,stream>>>(arB, arA);
        mfk_f23<1,8><<<dim3(16,P),256,0,stream>>>(arA, arB);
        if (G < NCH){
            int bBase, bCnt, eStart, eCount;
            if (G >= 32){ bBase = g0/32; bCnt = G/32; eStart = 0; eCount = 32; }
            else        { bBase = g0/32; bCnt = 1; eStart = g0 % 32; eCount = G; }
            int addTo = (eStart != 0);
            mfk_accum<<<dim3(128,bCnt),256,0,stream>>>(arB, located, g0, eStart, eCount, bBase, addTo);
        }
    }

    // wet/dry chain (batch 4 -> 2 pairs)
    if (G == NCH){
        mfk_dryacc_f01<<<dim3(16,4),256,0,stream>>>(arB, rmA, IR, located, arA);
    } else {
        mfk_dry_f01<<<dim3(16,4),256,0,stream>>>(located, rmA, IR, arA);
    }
    mfk_f23<-1,16><<<dim3(16,4),256,0,stream>>>(arA, arB);
    mfk_prod_f01<<<dim3(16,2),256,0,stream>>>(arB, arA);
    mfk_f23_final<<<dim3(16,2),256,0,stream>>>(arA, located, mxA, out);
}